// Round 2
// baseline (4205.591 us; speedup 1.0000x reference)
//
#include <hip/hip_runtime.h>
#include <hip/hip_bf16.h>
#include <math.h>

#define N_NODES 100000
#define N_EDGES 1600000
#define EP (N_EDGES + N_NODES)   // edges + self loops
#define F_IN 256
#define HIDDEN 32
#define HEADS 4
#define D1 (HEADS*HIDDEN)        // 128
#define NC 16
#define NEG_SLOPE 0.2f

// ---------------- workspace layout (bytes) ----------------
// layer-1 era:
//   h1   [N,128] f32 @ 0          (51,200,000)
//   agg1 [N,128] f32 @ 51,200,000 (51,200,000)
//   as1  [N,4]   f32 @ 102,400,000 (1,600,000)
//   ad1  [N,4]   f32 @ 104,000,000 (1,600,000)
//   m1   [N,4]   u32 @ 105,600,000 (1,600,000)
//   den1 [N,4]   f32 @ 107,200,000 (1,600,000)
//   ex1  [EP,4]  f32 @ 108,800,000 (27,200,000)  -> total 136,000,000
// layer-2 era (aliased into dead h1 region; memset AFTER k_agg1):
//   h2   [N,16] @ 0          as2 [N] @ 6,400,000   ad2 [N] @ 6,800,000
//   m2   [N]    @ 7,200,000  den2[N] @ 7,600,000   agg2[N,16] @ 8,000,000
//   ex2  [EP]   @ 14,400,000

__device__ __forceinline__ unsigned ford(float f) {
    unsigned u = __float_as_uint(f);
    return (u & 0x80000000u) ? ~u : (u | 0x80000000u);
}
__device__ __forceinline__ float unford(unsigned u) {
    return __uint_as_float((u & 0x80000000u) ? (u & 0x7fffffffu) : ~u);
}
__device__ __forceinline__ float lrelu(float x) { return x > 0.f ? x : NEG_SLOPE * x; }

__device__ __forceinline__ void edge_sd(const int* __restrict__ ei, int e, int& src, int& dst) {
    if (e < N_EDGES) { src = ei[e]; dst = ei[N_EDGES + e]; }
    else             { src = e - N_EDGES; dst = src; }
}

// ---------------- K1: h1 = x @ W1, fused as1/ad1 ----------------
// 256 thr, 32 nodes/block, 4 nodes/thread, W1 staged in 64-row chunks.
__global__ __launch_bounds__(256) void k_gemm1(
    const float* __restrict__ x, const float* __restrict__ W1,
    const float* __restrict__ a_src1, const float* __restrict__ a_dst1,
    float* __restrict__ h1, float* __restrict__ as1, float* __restrict__ ad1)
{
    __shared__ float xs[32 * 256];   // 32 KB
    __shared__ float wsm[64 * 128];  // 32 KB
    const int tid = threadIdx.x;
    const int base = blockIdx.x * 32;
    const int nl = tid >> 5, cg = tid & 31;

    {   // stage x rows [base, base+32): 8192 contiguous floats
        const float4* xb = (const float4*)(x + (size_t)base * 256);
        float4* xd = (float4*)xs;
        #pragma unroll
        for (int i = 0; i < 8; ++i) xd[tid + i * 256] = xb[tid + i * 256];
    }

    float4 acc[4];
    #pragma unroll
    for (int j = 0; j < 4; ++j) acc[j] = make_float4(0.f, 0.f, 0.f, 0.f);

    for (int kc = 0; kc < 4; ++kc) {
        __syncthreads();
        {   // stage W1 rows [kc*64, kc*64+64): 8192 contiguous floats
            const float4* wb = (const float4*)(W1 + (size_t)kc * 64 * 128);
            float4* wd = (float4*)wsm;
            #pragma unroll
            for (int i = 0; i < 8; ++i) wd[tid + i * 256] = wb[tid + i * 256];
        }
        __syncthreads();
        const int kofs = kc * 64;
        #pragma unroll 16
        for (int k = 0; k < 64; ++k) {
            const float4 wv = ((const float4*)wsm)[k * 32 + cg];
            #pragma unroll
            for (int j = 0; j < 4; ++j) {
                const float xv = xs[(nl + 8 * j) * 256 + kofs + k];
                acc[j].x = fmaf(xv, wv.x, acc[j].x);
                acc[j].y = fmaf(xv, wv.y, acc[j].y);
                acc[j].z = fmaf(xv, wv.z, acc[j].z);
                acc[j].w = fmaf(xv, wv.w, acc[j].w);
            }
        }
    }

    const int head = cg >> 3, pos = cg & 7;
    const float4 asv = ((const float4*)a_src1)[head * 8 + pos];
    const float4 adv = ((const float4*)a_dst1)[head * 8 + pos];
    #pragma unroll
    for (int j = 0; j < 4; ++j) {
        const int n = base + nl + 8 * j;
        ((float4*)(h1 + (size_t)n * 128))[cg] = acc[j];
        float ps = acc[j].x * asv.x + acc[j].y * asv.y + acc[j].z * asv.z + acc[j].w * asv.w;
        float pd = acc[j].x * adv.x + acc[j].y * adv.y + acc[j].z * adv.z + acc[j].w * adv.w;
        ps += __shfl_xor(ps, 1); ps += __shfl_xor(ps, 2); ps += __shfl_xor(ps, 4);
        pd += __shfl_xor(pd, 1); pd += __shfl_xor(pd, 2); pd += __shfl_xor(pd, 4);
        if (pos == 0) { as1[n * 4 + head] = ps; ad1[n * 4 + head] = pd; }
    }
}

// ---------------- K2: segment max (layer 1) ----------------
__global__ __launch_bounds__(256) void k_edge_max1(
    const int* __restrict__ ei, const float* __restrict__ as1,
    const float* __restrict__ ad1, unsigned* __restrict__ m1)
{
    const int e = blockIdx.x * 256 + threadIdx.x;
    if (e >= EP) return;
    int src, dst; edge_sd(ei, e, src, dst);
    const float4 s = ((const float4*)as1)[src];
    const float4 d = ((const float4*)ad1)[dst];
    unsigned* mp = m1 + (size_t)dst * 4;
    atomicMax(mp + 0, ford(lrelu(s.x + d.x)));
    atomicMax(mp + 1, ford(lrelu(s.y + d.y)));
    atomicMax(mp + 2, ford(lrelu(s.z + d.z)));
    atomicMax(mp + 3, ford(lrelu(s.w + d.w)));
}

// ---------------- K3: exp + segment sum (layer 1) ----------------
__global__ __launch_bounds__(256) void k_edge_exp1(
    const int* __restrict__ ei, const float* __restrict__ as1,
    const float* __restrict__ ad1, const unsigned* __restrict__ m1,
    float* __restrict__ den1, float* __restrict__ ex1)
{
    const int e = blockIdx.x * 256 + threadIdx.x;
    if (e >= EP) return;
    int src, dst; edge_sd(ei, e, src, dst);
    const float4 s = ((const float4*)as1)[src];
    const float4 d = ((const float4*)ad1)[dst];
    const uint4 mv = ((const uint4*)m1)[dst];
    float e0 = expf(lrelu(s.x + d.x) - unford(mv.x));
    float e1 = expf(lrelu(s.y + d.y) - unford(mv.y));
    float e2 = expf(lrelu(s.z + d.z) - unford(mv.z));
    float e3 = expf(lrelu(s.w + d.w) - unford(mv.w));
    ((float4*)ex1)[e] = make_float4(e0, e1, e2, e3);
    float* dp = den1 + (size_t)dst * 4;
    unsafeAtomicAdd(dp + 0, e0);
    unsafeAtomicAdd(dp + 1, e1);
    unsafeAtomicAdd(dp + 2, e2);
    unsafeAtomicAdd(dp + 3, e3);
}

// ---------------- K4: weighted scatter-add (layer 1) ----------------
// 32 threads per edge, 4 cols each.
__global__ __launch_bounds__(256) void k_agg1(
    const int* __restrict__ ei, const float* __restrict__ h1,
    const float* __restrict__ ex1, const float* __restrict__ den1,
    float* __restrict__ agg1)
{
    const int item = blockIdx.x * 256 + threadIdx.x;
    const int e = item >> 5, q = item & 31;
    int src, dst; edge_sd(ei, e, src, dst);
    const int k = q >> 3;
    const float alpha = ex1[(size_t)e * 4 + k] / (den1[(size_t)dst * 4 + k] + 1e-16f);
    const float4 hv = ((const float4*)(h1 + (size_t)src * 128))[q];
    float* ap = agg1 + (size_t)dst * 128 + q * 4;
    unsafeAtomicAdd(ap + 0, hv.x * alpha);
    unsafeAtomicAdd(ap + 1, hv.y * alpha);
    unsafeAtomicAdd(ap + 2, hv.z * alpha);
    unsafeAtomicAdd(ap + 3, hv.w * alpha);
}

// ---------------- K5: h2 = elu(agg1+b1) @ W2, fused as2/ad2 ----------------
__global__ __launch_bounds__(256) void k_gemm2(
    const float* __restrict__ agg1, const float* __restrict__ b1,
    const float* __restrict__ W2, const float* __restrict__ a_src2,
    const float* __restrict__ a_dst2,
    float* __restrict__ h2, float* __restrict__ as2, float* __restrict__ ad2)
{
    __shared__ float w2s[128 * 16];
    __shared__ float xs2[16 * 132];
    const int tid = threadIdx.x;
    const int base = blockIdx.x * 16;
    {   // stage W2 (2048 floats)
        const float4* wb = (const float4*)W2;
        float4* wd = (float4*)w2s;
        #pragma unroll
        for (int i = 0; i < 2; ++i) wd[tid + i * 256] = wb[tid + i * 256];
    }
    // stage elu(agg1+b1) rows [base, base+16)
    #pragma unroll
    for (int i = 0; i < 2; ++i) {
        const int idx = tid + i * 256;      // float4 index into [16][128]
        const int nl = idx >> 5;
        const int c4 = idx & 31;
        float4 v = ((const float4*)(agg1 + (size_t)(base + nl) * 128))[c4];
        const float4 b = ((const float4*)b1)[c4];
        v.x += b.x; v.y += b.y; v.z += b.z; v.w += b.w;
        v.x = v.x > 0.f ? v.x : expm1f(v.x);
        v.y = v.y > 0.f ? v.y : expm1f(v.y);
        v.z = v.z > 0.f ? v.z : expm1f(v.z);
        v.w = v.w > 0.f ? v.w : expm1f(v.w);
        *((float4*)(xs2 + nl * 132 + c4 * 4)) = v;
    }
    __syncthreads();
    const int nl = tid >> 4, c = tid & 15;
    float acc = 0.f;
    #pragma unroll
    for (int k = 0; k < 128; ++k)
        acc = fmaf(xs2[nl * 132 + k], w2s[k * 16 + c], acc);
    const int n = base + nl;
    h2[(size_t)n * 16 + c] = acc;
    float ps = acc * a_src2[c];
    float pd = acc * a_dst2[c];
    ps += __shfl_xor(ps, 1); ps += __shfl_xor(ps, 2); ps += __shfl_xor(ps, 4); ps += __shfl_xor(ps, 8);
    pd += __shfl_xor(pd, 1); pd += __shfl_xor(pd, 2); pd += __shfl_xor(pd, 4); pd += __shfl_xor(pd, 8);
    if (c == 0) { as2[n] = ps; ad2[n] = pd; }
}

// ---------------- K6: segment max (layer 2) ----------------
__global__ __launch_bounds__(256) void k_edge_max2(
    const int* __restrict__ ei, const float* __restrict__ as2,
    const float* __restrict__ ad2, unsigned* __restrict__ m2)
{
    const int e = blockIdx.x * 256 + threadIdx.x;
    if (e >= EP) return;
    int src, dst; edge_sd(ei, e, src, dst);
    atomicMax(m2 + dst, ford(lrelu(as2[src] + ad2[dst])));
}

// ---------------- K7: exp + segment sum (layer 2) ----------------
__global__ __launch_bounds__(256) void k_edge_exp2(
    const int* __restrict__ ei, const float* __restrict__ as2,
    const float* __restrict__ ad2, const unsigned* __restrict__ m2,
    float* __restrict__ den2, float* __restrict__ ex2)
{
    const int e = blockIdx.x * 256 + threadIdx.x;
    if (e >= EP) return;
    int src, dst; edge_sd(ei, e, src, dst);
    const float ex = expf(lrelu(as2[src] + ad2[dst]) - unford(m2[dst]));
    ex2[e] = ex;
    unsafeAtomicAdd(den2 + dst, ex);
}

// ---------------- K8: weighted scatter-add (layer 2) ----------------
// 4 threads per edge, 4 cols each.
__global__ __launch_bounds__(256) void k_agg2(
    const int* __restrict__ ei, const float* __restrict__ h2,
    const float* __restrict__ ex2, const float* __restrict__ den2,
    float* __restrict__ agg2)
{
    const int item = blockIdx.x * 256 + threadIdx.x;
    if (item >= EP * 4) return;
    const int e = item >> 2, q = item & 3;
    int src, dst; edge_sd(ei, e, src, dst);
    const float alpha = ex2[e] / (den2[dst] + 1e-16f);
    const float4 hv = ((const float4*)(h2 + (size_t)src * 16))[q];
    float* ap = agg2 + (size_t)dst * 16 + q * 4;
    unsafeAtomicAdd(ap + 0, hv.x * alpha);
    unsafeAtomicAdd(ap + 1, hv.y * alpha);
    unsafeAtomicAdd(ap + 2, hv.z * alpha);
    unsafeAtomicAdd(ap + 3, hv.w * alpha);
}

// ---------------- K9: out = log_softmax(agg2 + b2) ----------------
__global__ __launch_bounds__(256) void k_out(
    const float* __restrict__ agg2, const float* __restrict__ b2,
    float* __restrict__ out)
{
    const int tid = threadIdx.x;
    const int n = blockIdx.x * 16 + (tid >> 4);
    const int c = tid & 15;
    const float v = agg2[(size_t)n * 16 + c] + b2[c];
    float m = v;
    m = fmaxf(m, __shfl_xor(m, 1)); m = fmaxf(m, __shfl_xor(m, 2));
    m = fmaxf(m, __shfl_xor(m, 4)); m = fmaxf(m, __shfl_xor(m, 8));
    float s = expf(v - m);
    s += __shfl_xor(s, 1); s += __shfl_xor(s, 2);
    s += __shfl_xor(s, 4); s += __shfl_xor(s, 8);
    out[(size_t)n * 16 + c] = v - m - logf(s);
}

extern "C" void kernel_launch(void* const* d_in, const int* in_sizes, int n_in,
                              void* d_out, int out_size, void* d_ws, size_t ws_size,
                              hipStream_t stream) {
    const float* x      = (const float*)d_in[0];
    const float* W1     = (const float*)d_in[1];
    const float* a_src1 = (const float*)d_in[2];
    const float* a_dst1 = (const float*)d_in[3];
    const float* b1     = (const float*)d_in[4];
    const float* W2     = (const float*)d_in[5];
    const float* a_src2 = (const float*)d_in[6];
    const float* a_dst2 = (const float*)d_in[7];
    const float* b2     = (const float*)d_in[8];
    const int*   ei     = (const int*)d_in[9];
    float* out = (float*)d_out;
    char* ws = (char*)d_ws;

    float*    h1   = (float*)(ws + 0);
    float*    agg1 = (float*)(ws + 51200000);
    float*    as1  = (float*)(ws + 102400000);
    float*    ad1  = (float*)(ws + 104000000);
    unsigned* m1   = (unsigned*)(ws + 105600000);
    float*    den1 = (float*)(ws + 107200000);
    float*    ex1  = (float*)(ws + 108800000);
    // layer-2 era (alias dead h1 region):
    float*    h2   = (float*)(ws + 0);
    float*    as2  = (float*)(ws + 6400000);
    float*    ad2  = (float*)(ws + 6800000);
    unsigned* m2   = (unsigned*)(ws + 7200000);
    float*    den2 = (float*)(ws + 7600000);
    float*    agg2 = (float*)(ws + 8000000);
    float*    ex2  = (float*)(ws + 14400000);

    // layer-1 zero-init (m1 ordered-uint identity is 0)
    hipMemsetAsync(m1, 0, 3200000, stream);           // m1 + den1 (adjacent)
    hipMemsetAsync(agg1, 0, 51200000, stream);

    const int EB = (EP + 255) / 256;
    k_gemm1<<<3125, 256, 0, stream>>>(x, W1, a_src1, a_dst1, h1, as1, ad1);
    k_edge_max1<<<EB, 256, 0, stream>>>(ei, as1, ad1, m1);
    k_edge_exp1<<<EB, 256, 0, stream>>>(ei, as1, ad1, m1, den1, ex1);
    k_agg1<<<EP * 32 / 256, 256, 0, stream>>>(ei, h1, ex1, den1, agg1);

    // layer-2 zero-init AFTER k_agg1 (aliases old h1 region): m2+den2+agg2
    hipMemsetAsync(m2, 0, 7200000, stream);

    k_gemm2<<<6250, 256, 0, stream>>>(agg1, b1, W2, a_src2, a_dst2, h2, as2, ad2);
    k_edge_max2<<<EB, 256, 0, stream>>>(ei, as2, ad2, m2);
    k_edge_exp2<<<EB, 256, 0, stream>>>(ei, as2, ad2, m2, den2, ex2);
    k_agg2<<<(EP * 4 + 255) / 256, 256, 0, stream>>>(ei, h2, ex2, den2, agg2);
    k_out<<<6250, 256, 0, stream>>>(agg2, b2, out);
}

// Round 3
// 736.619 us; speedup vs baseline: 5.7093x; 5.7093x over previous
//
#include <hip/hip_runtime.h>
#include <hip/hip_bf16.h>
#include <math.h>

#define N_NODES 100000
#define N_EDGES 1600000
#define EP (N_EDGES + N_NODES)   // edges + self loops
#define F_IN 256
#define HIDDEN 32
#define HEADS 4
#define D1 (HEADS*HIDDEN)        // 128
#define NC 16
#define NEG_SLOPE 0.2f
#define NBLK 391                 // ceil(N_NODES/256)

// ---------------- workspace layout (bytes) ----------------
// layer-1 era:
//   h1      [N,128] f32 @ 0           (51,200,000)
//   agg1    [N,128] f32 @ 51,200,000  (51,200,000)
//   as1     [N,4]   f32 @ 102,400,000 (1,600,000)
//   ad1     [N,4]   f32 @ 104,000,000 (1,600,000)
//   row_ptr [N+1]   i32 @ 105,600,000 (400,016 padded)
//   cur/deg [N]     i32 @ 106,000,016 (400,000)
//   partials[512]   i32 @ 106,400,016 (2,048)
//   csr_src [EP]    i32 @ 106,402,064 (6,800,000) -> ends 113,202,064
// layer-2 era (aliased into dead h1 region, written after k_agg1f):
//   h2 [N,16] @ 0   as2 [N] @ 6,400,000   ad2 [N] @ 6,800,000   agg2 [N,16] @ 7,200,000

__device__ __forceinline__ float lrelu(float x) { return x > 0.f ? x : NEG_SLOPE * x; }

// ---------------- CSR build ----------------
__global__ __launch_bounds__(256) void k_deg(const int* __restrict__ ei, int* __restrict__ deg) {
    const int e = blockIdx.x * 256 + threadIdx.x;
    if (e >= EP) return;
    const int dst = (e < N_EDGES) ? ei[N_EDGES + e] : (e - N_EDGES);
    atomicAdd(deg + dst, 1);
}

__global__ __launch_bounds__(256) void k_scan1(const int* __restrict__ deg, int* __restrict__ partials) {
    __shared__ int sb[256];
    const int i = blockIdx.x * 256 + threadIdx.x;
    sb[threadIdx.x] = (i < N_NODES) ? deg[i] : 0;
    __syncthreads();
    for (int off = 128; off > 0; off >>= 1) {
        if (threadIdx.x < off) sb[threadIdx.x] += sb[threadIdx.x + off];
        __syncthreads();
    }
    if (threadIdx.x == 0) partials[blockIdx.x] = sb[0];
}

__global__ __launch_bounds__(512) void k_scan2(int* __restrict__ partials) {
    __shared__ int sb[512];
    const int tid = threadIdx.x;
    const int v = (tid < NBLK) ? partials[tid] : 0;
    sb[tid] = v;
    __syncthreads();
    for (int off = 1; off < 512; off <<= 1) {
        const int t = (tid >= off) ? sb[tid - off] : 0;
        __syncthreads();
        sb[tid] += t;
        __syncthreads();
    }
    if (tid < NBLK) partials[tid] = sb[tid] - v;   // exclusive
}

__global__ __launch_bounds__(256) void k_scan3(const int* __restrict__ partials,
                                               int* __restrict__ deg_then_cur,
                                               int* __restrict__ row_ptr) {
    __shared__ int sb[256];
    const int tid = threadIdx.x;
    const int i = blockIdx.x * 256 + tid;
    const int v = (i < N_NODES) ? deg_then_cur[i] : 0;
    sb[tid] = v;
    __syncthreads();
    for (int off = 1; off < 256; off <<= 1) {
        const int t = (tid >= off) ? sb[tid - off] : 0;
        __syncthreads();
        sb[tid] += t;
        __syncthreads();
    }
    const int excl = sb[tid] - v + partials[blockIdx.x];
    if (i <= N_NODES) row_ptr[i] = excl;          // i==N_NODES lands on EP
    if (i < N_NODES) deg_then_cur[i] = excl;      // becomes scatter cursor
}

__global__ __launch_bounds__(256) void k_scatter(const int* __restrict__ ei,
                                                 int* __restrict__ cur,
                                                 int* __restrict__ csr_src) {
    const int e = blockIdx.x * 256 + threadIdx.x;
    if (e >= EP) return;
    int src, dst;
    if (e < N_EDGES) { src = ei[e]; dst = ei[N_EDGES + e]; }
    else             { src = e - N_EDGES; dst = src; }
    const int pos = atomicAdd(cur + dst, 1);
    csr_src[pos] = src;
}

// ---------------- K1: h1 = x @ W1, fused as1/ad1 ----------------
__global__ __launch_bounds__(256) void k_gemm1(
    const float* __restrict__ x, const float* __restrict__ W1,
    const float* __restrict__ a_src1, const float* __restrict__ a_dst1,
    float* __restrict__ h1, float* __restrict__ as1, float* __restrict__ ad1)
{
    __shared__ float xs[32 * 256];   // 32 KB
    __shared__ float wsm[64 * 128];  // 32 KB
    const int tid = threadIdx.x;
    const int base = blockIdx.x * 32;
    const int nl = tid >> 5, cg = tid & 31;

    {   // stage x rows [base, base+32)
        const float4* xb = (const float4*)(x + (size_t)base * 256);
        float4* xd = (float4*)xs;
        #pragma unroll
        for (int i = 0; i < 8; ++i) xd[tid + i * 256] = xb[tid + i * 256];
    }

    float4 acc[4];
    #pragma unroll
    for (int j = 0; j < 4; ++j) acc[j] = make_float4(0.f, 0.f, 0.f, 0.f);

    for (int kc = 0; kc < 4; ++kc) {
        __syncthreads();
        {   // stage W1 rows [kc*64, kc*64+64)
            const float4* wb = (const float4*)(W1 + (size_t)kc * 64 * 128);
            float4* wd = (float4*)wsm;
            #pragma unroll
            for (int i = 0; i < 8; ++i) wd[tid + i * 256] = wb[tid + i * 256];
        }
        __syncthreads();
        const int kofs = kc * 64;
        #pragma unroll 16
        for (int k = 0; k < 64; ++k) {
            const float4 wv = ((const float4*)wsm)[k * 32 + cg];
            #pragma unroll
            for (int j = 0; j < 4; ++j) {
                const float xv = xs[(nl + 8 * j) * 256 + kofs + k];
                acc[j].x = fmaf(xv, wv.x, acc[j].x);
                acc[j].y = fmaf(xv, wv.y, acc[j].y);
                acc[j].z = fmaf(xv, wv.z, acc[j].z);
                acc[j].w = fmaf(xv, wv.w, acc[j].w);
            }
        }
    }

    const int head = cg >> 3, pos = cg & 7;
    const float4 asv = ((const float4*)a_src1)[head * 8 + pos];
    const float4 adv = ((const float4*)a_dst1)[head * 8 + pos];
    #pragma unroll
    for (int j = 0; j < 4; ++j) {
        const int n = base + nl + 8 * j;
        ((float4*)(h1 + (size_t)n * 128))[cg] = acc[j];
        float ps = acc[j].x * asv.x + acc[j].y * asv.y + acc[j].z * asv.z + acc[j].w * asv.w;
        float pd = acc[j].x * adv.x + acc[j].y * adv.y + acc[j].z * adv.z + acc[j].w * adv.w;
        ps += __shfl_xor(ps, 1); ps += __shfl_xor(ps, 2); ps += __shfl_xor(ps, 4);
        pd += __shfl_xor(pd, 1); pd += __shfl_xor(pd, 2); pd += __shfl_xor(pd, 4);
        if (pos == 0) { as1[n * 4 + head] = ps; ad1[n * 4 + head] = pd; }
    }
}

// ---------------- K2: fused softmax + aggregation (layer 1) ----------------
// One wave per dst node; 4 dst per 256-thread block.
__global__ __launch_bounds__(256) void k_agg1f(
    const int* __restrict__ row_ptr, const int* __restrict__ csr_src,
    const float* __restrict__ as1, const float* __restrict__ ad1,
    const float* __restrict__ h1, float* __restrict__ agg1)
{
    const int dst  = blockIdx.x * 4 + (threadIdx.x >> 6);
    const int lane = threadIdx.x & 63;
    const int start = row_ptr[dst], end = row_ptr[dst + 1];

    // ---- phase 1: online softmax stats per head ----
    const int eh = lane >> 2;        // edge slot 0..15
    const int k  = lane & 3;         // head for phase 1
    const float adk = ad1[dst * 4 + k];
    float m = -1e30f, den = 0.f;
    for (int i = start + eh; i < end; i += 16) {
        const int src = csr_src[i];
        const float s = lrelu(as1[src * 4 + k] + adk);
        const float M = fmaxf(m, s);
        den = den * __expf(m - M) + __expf(s - M);
        m = M;
    }
    // butterfly merge across the 16 lanes of each head (stride 4)
    #pragma unroll
    for (int mask = 4; mask < 64; mask <<= 1) {
        const float mo = __shfl_xor(m, mask);
        const float dn = __shfl_xor(den, mask);
        const float M  = fmaxf(m, mo);
        den = den * __expf(m - M) + dn * __expf(mo - M);
        m = M;
    }
    // redistribute stats to this lane's output head (lane h holds head h's stats)
    const int oh = lane >> 4;                 // output head for phase 2 (2 cols/lane)
    const float mh   = __shfl(m, oh);
    const float rden = 1.f / (__shfl(den, oh) + 1e-16f);
    const float adh  = ad1[dst * 4 + oh];

    // ---- phase 2: weighted gather ----
    float2 acc = make_float2(0.f, 0.f);
    const float2* h1v = (const float2*)h1;
    for (int i = start; i < end; ++i) {
        const int src = csr_src[i];
        const float s = lrelu(as1[src * 4 + oh] + adh);
        const float a = __expf(s - mh) * rden;
        const float2 hv = h1v[(size_t)src * 64 + lane];
        acc.x = fmaf(a, hv.x, acc.x);
        acc.y = fmaf(a, hv.y, acc.y);
    }
    ((float2*)agg1)[(size_t)dst * 64 + lane] = acc;
}

// ---------------- K3: h2 = elu(agg1+b1) @ W2, fused as2/ad2 ----------------
__global__ __launch_bounds__(256) void k_gemm2(
    const float* __restrict__ agg1, const float* __restrict__ b1,
    const float* __restrict__ W2, const float* __restrict__ a_src2,
    const float* __restrict__ a_dst2,
    float* __restrict__ h2, float* __restrict__ as2, float* __restrict__ ad2)
{
    __shared__ float w2s[128 * 16];
    __shared__ float xs2[16 * 132];
    const int tid = threadIdx.x;
    const int base = blockIdx.x * 16;
    {   // stage W2 (2048 floats)
        const float4* wb = (const float4*)W2;
        float4* wd = (float4*)w2s;
        #pragma unroll
        for (int i = 0; i < 2; ++i) wd[tid + i * 256] = wb[tid + i * 256];
    }
    #pragma unroll
    for (int i = 0; i < 2; ++i) {
        const int idx = tid + i * 256;      // float4 index into [16][128]
        const int nl = idx >> 5;
        const int c4 = idx & 31;
        float4 v = ((const float4*)(agg1 + (size_t)(base + nl) * 128))[c4];
        const float4 b = ((const float4*)b1)[c4];
        v.x += b.x; v.y += b.y; v.z += b.z; v.w += b.w;
        v.x = v.x > 0.f ? v.x : expm1f(v.x);
        v.y = v.y > 0.f ? v.y : expm1f(v.y);
        v.z = v.z > 0.f ? v.z : expm1f(v.z);
        v.w = v.w > 0.f ? v.w : expm1f(v.w);
        *((float4*)(xs2 + nl * 132 + c4 * 4)) = v;
    }
    __syncthreads();
    const int nl = tid >> 4, c = tid & 15;
    float acc = 0.f;
    #pragma unroll
    for (int k = 0; k < 128; ++k)
        acc = fmaf(xs2[nl * 132 + k], w2s[k * 16 + c], acc);
    const int n = base + nl;
    h2[(size_t)n * 16 + c] = acc;
    float ps = acc * a_src2[c];
    float pd = acc * a_dst2[c];
    ps += __shfl_xor(ps, 1); ps += __shfl_xor(ps, 2); ps += __shfl_xor(ps, 4); ps += __shfl_xor(ps, 8);
    pd += __shfl_xor(pd, 1); pd += __shfl_xor(pd, 2); pd += __shfl_xor(pd, 4); pd += __shfl_xor(pd, 8);
    if (c == 0) { as2[n] = ps; ad2[n] = pd; }
}

// ---------------- K4: fused softmax + aggregation (layer 2) ----------------
// 16 lanes per dst node; 16 dst per 256-thread block.
__global__ __launch_bounds__(256) void k_agg2f(
    const int* __restrict__ row_ptr, const int* __restrict__ csr_src,
    const float* __restrict__ as2, const float* __restrict__ ad2,
    const float* __restrict__ h2, float* __restrict__ agg2)
{
    const int dst  = blockIdx.x * 16 + (threadIdx.x >> 4);
    const int lane = threadIdx.x & 15;
    const int start = row_ptr[dst], end = row_ptr[dst + 1];
    const float add = ad2[dst];

    // phase 1: online stats, one edge per lane, stride 16
    float m = -1e30f, den = 0.f;
    for (int i = start + lane; i < end; i += 16) {
        const float s = lrelu(as2[csr_src[i]] + add);
        const float M = fmaxf(m, s);
        den = den * __expf(m - M) + __expf(s - M);
        m = M;
    }
    #pragma unroll
    for (int mask = 1; mask < 16; mask <<= 1) {
        const float mo = __shfl_xor(m, mask);
        const float dn = __shfl_xor(den, mask);
        const float M  = fmaxf(m, mo);
        den = den * __expf(m - M) + dn * __expf(mo - M);
        m = M;
    }
    const float rden = 1.f / (den + 1e-16f);

    // phase 2: weighted gather (h2 is 6.4 MB -> L2-resident)
    float acc = 0.f;
    for (int i = start; i < end; ++i) {
        const int src = csr_src[i];
        const float s = lrelu(as2[src] + add);
        const float a = __expf(s - m) * rden;
        acc = fmaf(a, h2[(size_t)src * 16 + lane], acc);
    }
    agg2[(size_t)dst * 16 + lane] = acc;
}

// ---------------- K5: out = log_softmax(agg2 + b2) ----------------
__global__ __launch_bounds__(256) void k_out(
    const float* __restrict__ agg2, const float* __restrict__ b2,
    float* __restrict__ out)
{
    const int tid = threadIdx.x;
    const int n = blockIdx.x * 16 + (tid >> 4);
    const int c = tid & 15;
    const float v = agg2[(size_t)n * 16 + c] + b2[c];
    float m = v;
    m = fmaxf(m, __shfl_xor(m, 1)); m = fmaxf(m, __shfl_xor(m, 2));
    m = fmaxf(m, __shfl_xor(m, 4)); m = fmaxf(m, __shfl_xor(m, 8));
    float s = expf(v - m);
    s += __shfl_xor(s, 1); s += __shfl_xor(s, 2);
    s += __shfl_xor(s, 4); s += __shfl_xor(s, 8);
    out[(size_t)n * 16 + c] = v - m - logf(s);
}

extern "C" void kernel_launch(void* const* d_in, const int* in_sizes, int n_in,
                              void* d_out, int out_size, void* d_ws, size_t ws_size,
                              hipStream_t stream) {
    const float* x      = (const float*)d_in[0];
    const float* W1     = (const float*)d_in[1];
    const float* a_src1 = (const float*)d_in[2];
    const float* a_dst1 = (const float*)d_in[3];
    const float* b1     = (const float*)d_in[4];
    const float* W2     = (const float*)d_in[5];
    const float* a_src2 = (const float*)d_in[6];
    const float* a_dst2 = (const float*)d_in[7];
    const float* b2     = (const float*)d_in[8];
    const int*   ei     = (const int*)d_in[9];
    float* out = (float*)d_out;
    char* ws = (char*)d_ws;

    float* h1      = (float*)(ws + 0);
    float* agg1    = (float*)(ws + 51200000);
    float* as1     = (float*)(ws + 102400000);
    float* ad1     = (float*)(ws + 104000000);
    int*   row_ptr = (int*)(ws + 105600000);
    int*   cur     = (int*)(ws + 106000016);   // deg, then scatter cursor
    int*   partials= (int*)(ws + 106400016);
    int*   csr_src = (int*)(ws + 106402064);
    // layer-2 era (alias dead h1 region):
    float* h2   = (float*)(ws + 0);
    float* as2  = (float*)(ws + 6400000);
    float* ad2  = (float*)(ws + 6800000);
    float* agg2 = (float*)(ws + 7200000);

    const int EB = (EP + 255) / 256;

    // dense transform (independent of CSR build)
    k_gemm1<<<3125, 256, 0, stream>>>(x, W1, a_src1, a_dst1, h1, as1, ad1);

    // CSR build
    hipMemsetAsync(cur, 0, 400000, stream);
    k_deg<<<EB, 256, 0, stream>>>(ei, cur);
    k_scan1<<<NBLK, 256, 0, stream>>>(cur, partials);
    k_scan2<<<1, 512, 0, stream>>>(partials);
    k_scan3<<<NBLK, 256, 0, stream>>>(partials, cur, row_ptr);
    k_scatter<<<EB, 256, 0, stream>>>(ei, cur, csr_src);

    // layer 1 attention + aggregation
    k_agg1f<<<25000, 256, 0, stream>>>(row_ptr, csr_src, as1, ad1, h1, agg1);

    // layer 2
    k_gemm2<<<6250, 256, 0, stream>>>(agg1, b1, W2, a_src2, a_dst2, h2, as2, ad2);
    k_agg2f<<<6250, 256, 0, stream>>>(row_ptr, csr_src, as2, ad2, h2, agg2);
    k_out<<<6250, 256, 0, stream>>>(agg2, b2, out);
}

// Round 4
// 667.763 us; speedup vs baseline: 6.2980x; 1.1031x over previous
//
#include <hip/hip_runtime.h>
#include <hip/hip_bf16.h>
#include <math.h>

#define N_NODES 100000
#define N_EDGES 1600000
#define EP (N_EDGES + N_NODES)   // edges + self loops
#define F_IN 256
#define HIDDEN 32
#define HEADS 4
#define D1 (HEADS*HIDDEN)        // 128
#define NC 16
#define NEG_SLOPE 0.2f
#define NBLK 391                 // ceil(N_NODES/256)

// ---------------- workspace layout (bytes) ----------------
// layer-1 era:
//   h1b     [N,64]  u32 @ 0           (25,600,000)  packed bf16 pairs
//   agg1    [N,128] f32 @ 51,200,000  (51,200,000)
//   as1     [N,4]   f32 @ 102,400,000 (1,600,000)
//   ad1     [N,4]   f32 @ 104,000,000 (1,600,000)
//   row_ptr [N+1]   i32 @ 105,600,000 (400,016 padded)
//   cur/deg [N]     i32 @ 106,000,016 (400,000)
//   partials[512]   i32 @ 106,400,016 (2,048)
//   csr_src [EP]    i32 @ 106,402,064 (6,800,000) -> ends 113,202,064
// layer-2 era (aliased into dead h1b region, written after k_agg1f):
//   h2 [N,16] @ 0   as2 [N] @ 6,400,000   ad2 [N] @ 6,800,000   agg2 [N,16] @ 7,200,000

__device__ __forceinline__ float lrelu(float x) { return x > 0.f ? x : NEG_SLOPE * x; }

// pack two f32 -> two bf16 (RNE) in one u32: lo in [15:0], hi in [31:16]
__device__ __forceinline__ unsigned bfpack(float lo, float hi) {
    unsigned a = __float_as_uint(lo), b = __float_as_uint(hi);
    a = (a + 0x7fffu + ((a >> 16) & 1u)) >> 16;
    b = (b + 0x7fffu + ((b >> 16) & 1u)) & 0xffff0000u;
    return a | b;
}
__device__ __forceinline__ float bflo(unsigned v) { return __uint_as_float(v << 16); }
__device__ __forceinline__ float bfhi(unsigned v) { return __uint_as_float(v & 0xffff0000u); }

// ---------------- CSR build ----------------
__global__ __launch_bounds__(256) void k_deg(const int* __restrict__ ei, int* __restrict__ deg) {
    const int e = blockIdx.x * 256 + threadIdx.x;
    if (e >= EP) return;
    const int dst = (e < N_EDGES) ? ei[N_EDGES + e] : (e - N_EDGES);
    atomicAdd(deg + dst, 1);
}

__global__ __launch_bounds__(256) void k_scan1(const int* __restrict__ deg, int* __restrict__ partials) {
    __shared__ int sb[256];
    const int i = blockIdx.x * 256 + threadIdx.x;
    sb[threadIdx.x] = (i < N_NODES) ? deg[i] : 0;
    __syncthreads();
    for (int off = 128; off > 0; off >>= 1) {
        if (threadIdx.x < off) sb[threadIdx.x] += sb[threadIdx.x + off];
        __syncthreads();
    }
    if (threadIdx.x == 0) partials[blockIdx.x] = sb[0];
}

__global__ __launch_bounds__(512) void k_scan2(int* __restrict__ partials) {
    __shared__ int sb[512];
    const int tid = threadIdx.x;
    const int v = (tid < NBLK) ? partials[tid] : 0;
    sb[tid] = v;
    __syncthreads();
    for (int off = 1; off < 512; off <<= 1) {
        const int t = (tid >= off) ? sb[tid - off] : 0;
        __syncthreads();
        sb[tid] += t;
        __syncthreads();
    }
    if (tid < NBLK) partials[tid] = sb[tid] - v;   // exclusive
}

__global__ __launch_bounds__(256) void k_scan3(const int* __restrict__ partials,
                                               int* __restrict__ deg_then_cur,
                                               int* __restrict__ row_ptr) {
    __shared__ int sb[256];
    const int tid = threadIdx.x;
    const int i = blockIdx.x * 256 + tid;
    const int v = (i < N_NODES) ? deg_then_cur[i] : 0;
    sb[tid] = v;
    __syncthreads();
    for (int off = 1; off < 256; off <<= 1) {
        const int t = (tid >= off) ? sb[tid - off] : 0;
        __syncthreads();
        sb[tid] += t;
        __syncthreads();
    }
    const int excl = sb[tid] - v + partials[blockIdx.x];
    if (i <= N_NODES) row_ptr[i] = excl;          // i==N_NODES lands on EP
    if (i < N_NODES) deg_then_cur[i] = excl;      // becomes scatter cursor
}

__global__ __launch_bounds__(256) void k_scatter(const int* __restrict__ ei,
                                                 int* __restrict__ cur,
                                                 int* __restrict__ csr_src) {
    const int e = blockIdx.x * 256 + threadIdx.x;
    if (e >= EP) return;
    int src, dst;
    if (e < N_EDGES) { src = ei[e]; dst = ei[N_EDGES + e]; }
    else             { src = e - N_EDGES; dst = src; }
    const int pos = atomicAdd(cur + dst, 1);
    csr_src[pos] = src;
}

// ---------------- K1: h1 = x @ W1 (stored bf16-packed), fused as1/ad1 ----------------
__global__ __launch_bounds__(256) void k_gemm1(
    const float* __restrict__ x, const float* __restrict__ W1,
    const float* __restrict__ a_src1, const float* __restrict__ a_dst1,
    unsigned* __restrict__ h1b, float* __restrict__ as1, float* __restrict__ ad1)
{
    __shared__ float xs[32 * 256];   // 32 KB
    __shared__ float wsm[64 * 128];  // 32 KB
    const int tid = threadIdx.x;
    const int base = blockIdx.x * 32;
    const int nl = tid >> 5, cg = tid & 31;

    {   // stage x rows [base, base+32)
        const float4* xb = (const float4*)(x + (size_t)base * 256);
        float4* xd = (float4*)xs;
        #pragma unroll
        for (int i = 0; i < 8; ++i) xd[tid + i * 256] = xb[tid + i * 256];
    }

    float4 acc[4];
    #pragma unroll
    for (int j = 0; j < 4; ++j) acc[j] = make_float4(0.f, 0.f, 0.f, 0.f);

    for (int kc = 0; kc < 4; ++kc) {
        __syncthreads();
        {   // stage W1 rows [kc*64, kc*64+64)
            const float4* wb = (const float4*)(W1 + (size_t)kc * 64 * 128);
            float4* wd = (float4*)wsm;
            #pragma unroll
            for (int i = 0; i < 8; ++i) wd[tid + i * 256] = wb[tid + i * 256];
        }
        __syncthreads();
        const int kofs = kc * 64;
        #pragma unroll 16
        for (int k = 0; k < 64; ++k) {
            const float4 wv = ((const float4*)wsm)[k * 32 + cg];
            #pragma unroll
            for (int j = 0; j < 4; ++j) {
                const float xv = xs[(nl + 8 * j) * 256 + kofs + k];
                acc[j].x = fmaf(xv, wv.x, acc[j].x);
                acc[j].y = fmaf(xv, wv.y, acc[j].y);
                acc[j].z = fmaf(xv, wv.z, acc[j].z);
                acc[j].w = fmaf(xv, wv.w, acc[j].w);
            }
        }
    }

    const int head = cg >> 3, pos = cg & 7;
    const float4 asv = ((const float4*)a_src1)[head * 8 + pos];
    const float4 adv = ((const float4*)a_dst1)[head * 8 + pos];
    #pragma unroll
    for (int j = 0; j < 4; ++j) {
        const int n = base + nl + 8 * j;
        // packed bf16 store: cols (4cg,4cg+1) and (4cg+2,4cg+3)
        uint2 pv;
        pv.x = bfpack(acc[j].x, acc[j].y);
        pv.y = bfpack(acc[j].z, acc[j].w);
        ((uint2*)h1b)[(size_t)n * 32 + cg] = pv;
        float ps = acc[j].x * asv.x + acc[j].y * asv.y + acc[j].z * asv.z + acc[j].w * asv.w;
        float pd = acc[j].x * adv.x + acc[j].y * adv.y + acc[j].z * adv.z + acc[j].w * adv.w;
        ps += __shfl_xor(ps, 1); ps += __shfl_xor(ps, 2); ps += __shfl_xor(ps, 4);
        pd += __shfl_xor(pd, 1); pd += __shfl_xor(pd, 2); pd += __shfl_xor(pd, 4);
        if (pos == 0) { as1[n * 4 + head] = ps; ad1[n * 4 + head] = pd; }
    }
}

// ---------------- K2: fused softmax + aggregation (layer 1) ----------------
// One wave per dst node; 4 dst per 256-thread block.
__global__ __launch_bounds__(256) void k_agg1f(
    const int* __restrict__ row_ptr, const int* __restrict__ csr_src,
    const float* __restrict__ as1, const float* __restrict__ ad1,
    const unsigned* __restrict__ h1b, float* __restrict__ agg1)
{
    const int dst  = blockIdx.x * 4 + (threadIdx.x >> 6);
    const int lane = threadIdx.x & 63;
    const int start = row_ptr[dst], end = row_ptr[dst + 1];

    // ---- phase 1: online softmax stats per head ----
    const int eh = lane >> 2;        // edge slot 0..15
    const int k  = lane & 3;         // head for phase 1
    const float adk = ad1[dst * 4 + k];
    float m = -1e30f, den = 0.f;
    for (int i = start + eh; i < end; i += 16) {
        const int src = csr_src[i];
        const float s = lrelu(as1[src * 4 + k] + adk);
        const float M = fmaxf(m, s);
        den = den * __expf(m - M) + __expf(s - M);
        m = M;
    }
    // butterfly merge across the 16 lanes of each head (stride 4)
    #pragma unroll
    for (int mask = 4; mask < 64; mask <<= 1) {
        const float mo = __shfl_xor(m, mask);
        const float dn = __shfl_xor(den, mask);
        const float M  = fmaxf(m, mo);
        den = den * __expf(m - M) + dn * __expf(mo - M);
        m = M;
    }
    // redistribute stats to this lane's output head (lane h holds head h's stats)
    const int oh = lane >> 4;                 // output head for phase 2 (2 cols/lane)
    const float mh   = __shfl(m, oh);
    const float rden = 1.f / (__shfl(den, oh) + 1e-16f);
    const float adh  = ad1[dst * 4 + oh];

    // ---- phase 2: weighted gather (bf16 rows, 256 B/edge), unrolled x2 ----
    float2 acc = make_float2(0.f, 0.f);
    int i = start;
    for (; i + 1 < end; i += 2) {
        const int s0 = csr_src[i], s1 = csr_src[i + 1];
        const float e0 = lrelu(as1[s0 * 4 + oh] + adh);
        const float e1 = lrelu(as1[s1 * 4 + oh] + adh);
        const unsigned v0 = h1b[(size_t)s0 * 64 + lane];
        const unsigned v1 = h1b[(size_t)s1 * 64 + lane];
        const float a0 = __expf(e0 - mh) * rden;
        const float a1 = __expf(e1 - mh) * rden;
        acc.x = fmaf(a0, bflo(v0), acc.x);
        acc.y = fmaf(a0, bfhi(v0), acc.y);
        acc.x = fmaf(a1, bflo(v1), acc.x);
        acc.y = fmaf(a1, bfhi(v1), acc.y);
    }
    if (i < end) {
        const int s0 = csr_src[i];
        const float e0 = lrelu(as1[s0 * 4 + oh] + adh);
        const unsigned v0 = h1b[(size_t)s0 * 64 + lane];
        const float a0 = __expf(e0 - mh) * rden;
        acc.x = fmaf(a0, bflo(v0), acc.x);
        acc.y = fmaf(a0, bfhi(v0), acc.y);
    }
    ((float2*)agg1)[(size_t)dst * 64 + lane] = acc;
}

// ---------------- K3: h2 = elu(agg1+b1) @ W2, fused as2/ad2 ----------------
__global__ __launch_bounds__(256) void k_gemm2(
    const float* __restrict__ agg1, const float* __restrict__ b1,
    const float* __restrict__ W2, const float* __restrict__ a_src2,
    const float* __restrict__ a_dst2,
    float* __restrict__ h2, float* __restrict__ as2, float* __restrict__ ad2)
{
    __shared__ float w2s[128 * 16];
    __shared__ float xs2[16 * 132];
    const int tid = threadIdx.x;
    const int base = blockIdx.x * 16;
    {   // stage W2 (2048 floats)
        const float4* wb = (const float4*)W2;
        float4* wd = (float4*)w2s;
        #pragma unroll
        for (int i = 0; i < 2; ++i) wd[tid + i * 256] = wb[tid + i * 256];
    }
    #pragma unroll
    for (int i = 0; i < 2; ++i) {
        const int idx = tid + i * 256;      // float4 index into [16][128]
        const int nl = idx >> 5;
        const int c4 = idx & 31;
        float4 v = ((const float4*)(agg1 + (size_t)(base + nl) * 128))[c4];
        const float4 b = ((const float4*)b1)[c4];
        v.x += b.x; v.y += b.y; v.z += b.z; v.w += b.w;
        v.x = v.x > 0.f ? v.x : expm1f(v.x);
        v.y = v.y > 0.f ? v.y : expm1f(v.y);
        v.z = v.z > 0.f ? v.z : expm1f(v.z);
        v.w = v.w > 0.f ? v.w : expm1f(v.w);
        *((float4*)(xs2 + nl * 132 + c4 * 4)) = v;
    }
    __syncthreads();
    const int nl = tid >> 4, c = tid & 15;
    float acc = 0.f;
    #pragma unroll
    for (int k = 0; k < 128; ++k)
        acc = fmaf(xs2[nl * 132 + k], w2s[k * 16 + c], acc);
    const int n = base + nl;
    h2[(size_t)n * 16 + c] = acc;
    float ps = acc * a_src2[c];
    float pd = acc * a_dst2[c];
    ps += __shfl_xor(ps, 1); ps += __shfl_xor(ps, 2); ps += __shfl_xor(ps, 4); ps += __shfl_xor(ps, 8);
    pd += __shfl_xor(pd, 1); pd += __shfl_xor(pd, 2); pd += __shfl_xor(pd, 4); pd += __shfl_xor(pd, 8);
    if (c == 0) { as2[n] = ps; ad2[n] = pd; }
}

// ---------------- K4: fused softmax + aggregation (layer 2) ----------------
// 16 lanes per dst node; 16 dst per 256-thread block.
__global__ __launch_bounds__(256) void k_agg2f(
    const int* __restrict__ row_ptr, const int* __restrict__ csr_src,
    const float* __restrict__ as2, const float* __restrict__ ad2,
    const float* __restrict__ h2, float* __restrict__ agg2)
{
    const int dst  = blockIdx.x * 16 + (threadIdx.x >> 4);
    const int lane = threadIdx.x & 15;
    const int start = row_ptr[dst], end = row_ptr[dst + 1];
    const float add = ad2[dst];

    // phase 1: online stats, one edge per lane, stride 16
    float m = -1e30f, den = 0.f;
    for (int i = start + lane; i < end; i += 16) {
        const float s = lrelu(as2[csr_src[i]] + add);
        const float M = fmaxf(m, s);
        den = den * __expf(m - M) + __expf(s - M);
        m = M;
    }
    #pragma unroll
    for (int mask = 1; mask < 16; mask <<= 1) {
        const float mo = __shfl_xor(m, mask);
        const float dn = __shfl_xor(den, mask);
        const float M  = fmaxf(m, mo);
        den = den * __expf(m - M) + dn * __expf(mo - M);
        m = M;
    }
    const float rden = 1.f / (den + 1e-16f);

    // phase 2: weighted gather (h2 is 6.4 MB -> L2-resident)
    float acc = 0.f;
    for (int i = start; i < end; ++i) {
        const int src = csr_src[i];
        const float s = lrelu(as2[src] + add);
        const float a = __expf(s - m) * rden;
        acc = fmaf(a, h2[(size_t)src * 16 + lane], acc);
    }
    agg2[(size_t)dst * 16 + lane] = acc;
}

// ---------------- K5: out = log_softmax(agg2 + b2) ----------------
__global__ __launch_bounds__(256) void k_out(
    const float* __restrict__ agg2, const float* __restrict__ b2,
    float* __restrict__ out)
{
    const int tid = threadIdx.x;
    const int n = blockIdx.x * 16 + (tid >> 4);
    const int c = tid & 15;
    const float v = agg2[(size_t)n * 16 + c] + b2[c];
    float m = v;
    m = fmaxf(m, __shfl_xor(m, 1)); m = fmaxf(m, __shfl_xor(m, 2));
    m = fmaxf(m, __shfl_xor(m, 4)); m = fmaxf(m, __shfl_xor(m, 8));
    float s = expf(v - m);
    s += __shfl_xor(s, 1); s += __shfl_xor(s, 2);
    s += __shfl_xor(s, 4); s += __shfl_xor(s, 8);
    out[(size_t)n * 16 + c] = v - m - logf(s);
}

extern "C" void kernel_launch(void* const* d_in, const int* in_sizes, int n_in,
                              void* d_out, int out_size, void* d_ws, size_t ws_size,
                              hipStream_t stream) {
    const float* x      = (const float*)d_in[0];
    const float* W1     = (const float*)d_in[1];
    const float* a_src1 = (const float*)d_in[2];
    const float* a_dst1 = (const float*)d_in[3];
    const float* b1     = (const float*)d_in[4];
    const float* W2     = (const float*)d_in[5];
    const float* a_src2 = (const float*)d_in[6];
    const float* a_dst2 = (const float*)d_in[7];
    const float* b2     = (const float*)d_in[8];
    const int*   ei     = (const int*)d_in[9];
    float* out = (float*)d_out;
    char* ws = (char*)d_ws;

    unsigned* h1b   = (unsigned*)(ws + 0);
    float* agg1     = (float*)(ws + 51200000);
    float* as1      = (float*)(ws + 102400000);
    float* ad1      = (float*)(ws + 104000000);
    int*   row_ptr  = (int*)(ws + 105600000);
    int*   cur      = (int*)(ws + 106000016);   // deg, then scatter cursor
    int*   partials = (int*)(ws + 106400016);
    int*   csr_src  = (int*)(ws + 106402064);
    // layer-2 era (alias dead h1b region):
    float* h2   = (float*)(ws + 0);
    float* as2  = (float*)(ws + 6400000);
    float* ad2  = (float*)(ws + 6800000);
    float* agg2 = (float*)(ws + 7200000);

    const int EB = (EP + 255) / 256;

    // dense transform (independent of CSR build)
    k_gemm1<<<3125, 256, 0, stream>>>(x, W1, a_src1, a_dst1, h1b, as1, ad1);

    // CSR build
    hipMemsetAsync(cur, 0, 400000, stream);
    k_deg<<<EB, 256, 0, stream>>>(ei, cur);
    k_scan1<<<NBLK, 256, 0, stream>>>(cur, partials);
    k_scan2<<<1, 512, 0, stream>>>(partials);
    k_scan3<<<NBLK, 256, 0, stream>>>(partials, cur, row_ptr);
    k_scatter<<<EB, 256, 0, stream>>>(ei, cur, csr_src);

    // layer 1 attention + aggregation
    k_agg1f<<<25000, 256, 0, stream>>>(row_ptr, csr_src, as1, ad1, h1b, agg1);

    // layer 2
    k_gemm2<<<6250, 256, 0, stream>>>(agg1, b1, W2, a_src2, a_dst2, h2, as2, ad2);
    k_agg2f<<<6250, 256, 0, stream>>>(row_ptr, csr_src, as2, ad2, h2, agg2);
    k_out<<<6250, 256, 0, stream>>>(agg2, b2, out);
}

// Round 5
// 641.904 us; speedup vs baseline: 6.5517x; 1.0403x over previous
//
#include <hip/hip_runtime.h>
#include <hip/hip_bf16.h>
#include <math.h>

#define N_NODES 100000
#define N_EDGES 1600000
#define EP (N_EDGES + N_NODES)   // edges + self loops
#define F_IN 256
#define HIDDEN 32
#define HEADS 4
#define D1 (HEADS*HIDDEN)        // 128
#define NC 16
#define NEG_SLOPE 0.2f
#define NBLK 391                 // ceil(N_NODES/256)
#define NSTRIP 6250              // N_NODES / 16

typedef __attribute__((ext_vector_type(8))) short bf16x8;
typedef __attribute__((ext_vector_type(4))) float f32x4;

// ---------------- workspace layout (bytes) ----------------
// layer-1 era:
//   h1b     [N,64]  u32 @ 0           (25,600,000)  packed bf16 pairs
//   agg1    [N,128] f32 @ 51,200,000  (51,200,000)
//   as1     [N,4]   f32 @ 102,400,000 (1,600,000)
//   ad1     [N,4]   f32 @ 104,000,000 (1,600,000)
//   row_ptr [N+1]   i32 @ 105,600,000 (400,016 padded)
//   cur/deg [N]     i32 @ 106,000,016 (400,000)
//   partials[512]   i32 @ 106,400,016 (2,048)
//   csr_src [EP]    i32 @ 106,402,064 (6,800,000)
//   W1T     [128,256] bf16 @ 113,202,064 (65,536) -> ends 113,267,600
// layer-2 era (aliased into dead h1b region, written after k_agg1f):
//   h2 [N,16] @ 0   as2 [N] @ 6,400,000   ad2 [N] @ 6,800,000   agg2 [N,16] @ 7,200,000

__device__ __forceinline__ float lrelu(float x) { return x > 0.f ? x : NEG_SLOPE * x; }

// pack two f32 -> two bf16 (RNE) in one u32: lo in [15:0], hi in [31:16]
__device__ __forceinline__ unsigned bfpack(float lo, float hi) {
    unsigned a = __float_as_uint(lo), b = __float_as_uint(hi);
    a = (a + 0x7fffu + ((a >> 16) & 1u)) >> 16;
    b = (b + 0x7fffu + ((b >> 16) & 1u)) & 0xffff0000u;
    return a | b;
}
__device__ __forceinline__ unsigned short bf16r(float f) {
    unsigned a = __float_as_uint(f);
    return (unsigned short)((a + 0x7fffu + ((a >> 16) & 1u)) >> 16);
}
__device__ __forceinline__ float bflo(unsigned v) { return __uint_as_float(v << 16); }
__device__ __forceinline__ float bfhi(unsigned v) { return __uint_as_float(v & 0xffff0000u); }

// ---------------- CSR build ----------------
__global__ __launch_bounds__(256) void k_deg(const int* __restrict__ ei, int* __restrict__ deg) {
    const int e = blockIdx.x * 256 + threadIdx.x;
    if (e >= EP) return;
    const int dst = (e < N_EDGES) ? ei[N_EDGES + e] : (e - N_EDGES);
    atomicAdd(deg + dst, 1);
}

__global__ __launch_bounds__(256) void k_scan1(const int* __restrict__ deg, int* __restrict__ partials) {
    __shared__ int sb[256];
    const int i = blockIdx.x * 256 + threadIdx.x;
    sb[threadIdx.x] = (i < N_NODES) ? deg[i] : 0;
    __syncthreads();
    for (int off = 128; off > 0; off >>= 1) {
        if (threadIdx.x < off) sb[threadIdx.x] += sb[threadIdx.x + off];
        __syncthreads();
    }
    if (threadIdx.x == 0) partials[blockIdx.x] = sb[0];
}

__global__ __launch_bounds__(512) void k_scan2(int* __restrict__ partials) {
    __shared__ int sb[512];
    const int tid = threadIdx.x;
    const int v = (tid < NBLK) ? partials[tid] : 0;
    sb[tid] = v;
    __syncthreads();
    for (int off = 1; off < 512; off <<= 1) {
        const int t = (tid >= off) ? sb[tid - off] : 0;
        __syncthreads();
        sb[tid] += t;
        __syncthreads();
    }
    if (tid < NBLK) partials[tid] = sb[tid] - v;   // exclusive
}

__global__ __launch_bounds__(256) void k_scan3(const int* __restrict__ partials,
                                               int* __restrict__ deg_then_cur,
                                               int* __restrict__ row_ptr) {
    __shared__ int sb[256];
    const int tid = threadIdx.x;
    const int i = blockIdx.x * 256 + tid;
    const int v = (i < N_NODES) ? deg_then_cur[i] : 0;
    sb[tid] = v;
    __syncthreads();
    for (int off = 1; off < 256; off <<= 1) {
        const int t = (tid >= off) ? sb[tid - off] : 0;
        __syncthreads();
        sb[tid] += t;
        __syncthreads();
    }
    const int excl = sb[tid] - v + partials[blockIdx.x];
    if (i <= N_NODES) row_ptr[i] = excl;          // i==N_NODES lands on EP
    if (i < N_NODES) deg_then_cur[i] = excl;      // becomes scatter cursor
}

__global__ __launch_bounds__(256) void k_scatter(const int* __restrict__ ei,
                                                 int* __restrict__ cur,
                                                 int* __restrict__ csr_src) {
    const int e = blockIdx.x * 256 + threadIdx.x;
    if (e >= EP) return;
    int src, dst;
    if (e < N_EDGES) { src = ei[e]; dst = ei[N_EDGES + e]; }
    else             { src = e - N_EDGES; dst = src; }
    const int pos = atomicAdd(cur + dst, 1);
    csr_src[pos] = src;
}

// ---------------- W1 -> W1T bf16 [128][256] ----------------
__global__ __launch_bounds__(128) void k_w1t(const float* __restrict__ W1,
                                             unsigned short* __restrict__ W1T) {
    const int k = blockIdx.x;      // 0..255
    const int n = threadIdx.x;     // 0..127
    W1T[n * 256 + k] = bf16r(W1[k * 128 + n]);
}

// ---------------- K1: h1 = x @ W1 via MFMA bf16, fused as1/ad1 ----------------
// 4 waves/block, each wave computes one 16-row strip x 128 cols.
__global__ __launch_bounds__(256) void k_gemm1m(
    const float* __restrict__ x, const unsigned short* __restrict__ W1T,
    const float* __restrict__ a_src1, const float* __restrict__ a_dst1,
    unsigned* __restrict__ h1b, float* __restrict__ as1, float* __restrict__ ad1)
{
    const int s = blockIdx.x * 4 + (threadIdx.x >> 6);
    if (s >= NSTRIP) return;
    const int lane = threadIdx.x & 63;
    const int q = lane & 15, g = lane >> 4;
    const int base = s * 16;
    const int row = base + q;           // A fragment row for this lane
    const int kseg = g * 8;             // k sub-segment within each K=32 step

    f32x4 acc[8];
    #pragma unroll
    for (int t = 0; t < 8; ++t) acc[t] = (f32x4){0.f, 0.f, 0.f, 0.f};

    #pragma unroll
    for (int kk = 0; kk < 8; ++kk) {
        // A fragment: x[row][kk*32 + kseg .. +8), f32 -> bf16
        const float4* xp = (const float4*)(x + (size_t)row * 256 + kk * 32 + kseg);
        const float4 xa = xp[0], xb = xp[1];
        union { unsigned u[4]; bf16x8 v; } A;
        A.u[0] = bfpack(xa.x, xa.y);
        A.u[1] = bfpack(xa.z, xa.w);
        A.u[2] = bfpack(xb.x, xb.y);
        A.u[3] = bfpack(xb.z, xb.w);
        #pragma unroll
        for (int t = 0; t < 8; ++t) {
            // B fragment: W1T[t*16 + q][kk*32 + kseg .. +8)
            const bf16x8 B = *(const bf16x8*)(W1T + (size_t)(t * 16 + q) * 256 + kk * 32 + kseg);
            acc[t] = __builtin_amdgcn_mfma_f32_16x16x32_bf16(A.v, B, acc[t], 0, 0, 0);
        }
    }

    // ---- epilogue: as1/ad1 per-head dots ----
    float ps[4][4], pd[4][4];
    #pragma unroll
    for (int h = 0; h < 4; ++h)
        #pragma unroll
        for (int r = 0; r < 4; ++r) { ps[h][r] = 0.f; pd[h][r] = 0.f; }
    #pragma unroll
    for (int t = 0; t < 8; ++t) {
        const int col = t * 16 + q;
        const float av = a_src1[col];   // [4][32] flattens to col order
        const float dv = a_dst1[col];
        const int h = t >> 1;
        #pragma unroll
        for (int r = 0; r < 4; ++r) {
            ps[h][r] = fmaf(acc[t][r], av, ps[h][r]);
            pd[h][r] = fmaf(acc[t][r], dv, pd[h][r]);
        }
    }
    #pragma unroll
    for (int mask = 1; mask < 16; mask <<= 1) {
        #pragma unroll
        for (int h = 0; h < 4; ++h)
            #pragma unroll
            for (int r = 0; r < 4; ++r) {
                ps[h][r] += __shfl_xor(ps[h][r], mask);
                pd[h][r] += __shfl_xor(pd[h][r], mask);
            }
    }
    // lane q == h*4+r writes row (base + g*4 + r), head h (group g owns rows g*4..g*4+3)
    #pragma unroll
    for (int h = 0; h < 4; ++h)
        #pragma unroll
        for (int r = 0; r < 4; ++r)
            if (q == h * 4 + r) {
                const int n = base + g * 4 + r;
                as1[n * 4 + h] = ps[h][r];
                ad1[n * 4 + h] = pd[h][r];
            }

    // ---- h1b store: pack col pairs via shfl ----
    #pragma unroll
    for (int t = 0; t < 8; ++t) {
        #pragma unroll
        for (int r = 0; r < 4; ++r) {
            const float other = __shfl_xor(acc[t][r], 1);
            if (!(q & 1)) {
                const int n = base + g * 4 + r;
                h1b[(size_t)n * 64 + t * 8 + (q >> 1)] = bfpack(acc[t][r], other);
            }
        }
    }
}

// ---------------- K2: fused softmax + aggregation (layer 1) ----------------
// One wave per dst node; 4 dst per 256-thread block.
__global__ __launch_bounds__(256) void k_agg1f(
    const int* __restrict__ row_ptr, const int* __restrict__ csr_src,
    const float* __restrict__ as1, const float* __restrict__ ad1,
    const unsigned* __restrict__ h1b, float* __restrict__ agg1)
{
    const int dst  = blockIdx.x * 4 + (threadIdx.x >> 6);
    const int lane = threadIdx.x & 63;
    const int start = row_ptr[dst], end = row_ptr[dst + 1];

    // ---- phase 1: online softmax stats per head ----
    const int eh = lane >> 2;        // edge slot 0..15
    const int k  = lane & 3;         // head for phase 1
    const float adk = ad1[dst * 4 + k];
    float m = -1e30f, den = 0.f;
    for (int i = start + eh; i < end; i += 16) {
        const int src = csr_src[i];
        const float s = lrelu(as1[src * 4 + k] + adk);
        const float M = fmaxf(m, s);
        den = den * __expf(m - M) + __expf(s - M);
        m = M;
    }
    // butterfly merge across the 16 lanes of each head (stride 4)
    #pragma unroll
    for (int mask = 4; mask < 64; mask <<= 1) {
        const float mo = __shfl_xor(m, mask);
        const float dn = __shfl_xor(den, mask);
        const float M  = fmaxf(m, mo);
        den = den * __expf(m - M) + dn * __expf(mo - M);
        m = M;
    }
    // redistribute stats to this lane's output head (lane h holds head h's stats)
    const int oh = lane >> 4;                 // output head for phase 2 (2 cols/lane)
    const float mh   = __shfl(m, oh);
    const float rden = 1.f / (__shfl(den, oh) + 1e-16f);
    const float adh  = ad1[dst * 4 + oh];

    // ---- phase 2: weighted gather (bf16 rows, 256 B/edge), unrolled x2 ----
    float2 acc = make_float2(0.f, 0.f);
    int i = start;
    for (; i + 1 < end; i += 2) {
        const int s0 = csr_src[i], s1 = csr_src[i + 1];
        const float e0 = lrelu(as1[s0 * 4 + oh] + adh);
        const float e1 = lrelu(as1[s1 * 4 + oh] + adh);
        const unsigned v0 = h1b[(size_t)s0 * 64 + lane];
        const unsigned v1 = h1b[(size_t)s1 * 64 + lane];
        const float a0 = __expf(e0 - mh) * rden;
        const float a1 = __expf(e1 - mh) * rden;
        acc.x = fmaf(a0, bflo(v0), acc.x);
        acc.y = fmaf(a0, bfhi(v0), acc.y);
        acc.x = fmaf(a1, bflo(v1), acc.x);
        acc.y = fmaf(a1, bfhi(v1), acc.y);
    }
    if (i < end) {
        const int s0 = csr_src[i];
        const float e0 = lrelu(as1[s0 * 4 + oh] + adh);
        const unsigned v0 = h1b[(size_t)s0 * 64 + lane];
        const float a0 = __expf(e0 - mh) * rden;
        acc.x = fmaf(a0, bflo(v0), acc.x);
        acc.y = fmaf(a0, bfhi(v0), acc.y);
    }
    ((float2*)agg1)[(size_t)dst * 64 + lane] = acc;
}

// ---------------- K3: h2 = elu(agg1+b1) @ W2, fused as2/ad2 ----------------
__global__ __launch_bounds__(256) void k_gemm2(
    const float* __restrict__ agg1, const float* __restrict__ b1,
    const float* __restrict__ W2, const float* __restrict__ a_src2,
    const float* __restrict__ a_dst2,
    float* __restrict__ h2, float* __restrict__ as2, float* __restrict__ ad2)
{
    __shared__ float w2s[128 * 16];
    __shared__ float xs2[16 * 132];
    const int tid = threadIdx.x;
    const int base = blockIdx.x * 16;
    {   // stage W2 (2048 floats)
        const float4* wb = (const float4*)W2;
        float4* wd = (float4*)w2s;
        #pragma unroll
        for (int i = 0; i < 2; ++i) wd[tid + i * 256] = wb[tid + i * 256];
    }
    #pragma unroll
    for (int i = 0; i < 2; ++i) {
        const int idx = tid + i * 256;      // float4 index into [16][128]
        const int nl = idx >> 5;
        const int c4 = idx & 31;
        float4 v = ((const float4*)(agg1 + (size_t)(base + nl) * 128))[c4];
        const float4 b = ((const float4*)b1)[c4];
        v.x += b.x; v.y += b.y; v.z += b.z; v.w += b.w;
        v.x = v.x > 0.f ? v.x : expm1f(v.x);
        v.y = v.y > 0.f ? v.y : expm1f(v.y);
        v.z = v.z > 0.f ? v.z : expm1f(v.z);
        v.w = v.w > 0.f ? v.w : expm1f(v.w);
        *((float4*)(xs2 + nl * 132 + c4 * 4)) = v;
    }
    __syncthreads();
    const int nl = tid >> 4, c = tid & 15;
    float acc = 0.f;
    #pragma unroll
    for (int k = 0; k < 128; ++k)
        acc = fmaf(xs2[nl * 132 + k], w2s[k * 16 + c], acc);
    const int n = base + nl;
    h2[(size_t)n * 16 + c] = acc;
    float ps = acc * a_src2[c];
    float pd = acc * a_dst2[c];
    ps += __shfl_xor(ps, 1); ps += __shfl_xor(ps, 2); ps += __shfl_xor(ps, 4); ps += __shfl_xor(ps, 8);
    pd += __shfl_xor(pd, 1); pd += __shfl_xor(pd, 2); pd += __shfl_xor(pd, 4); pd += __shfl_xor(pd, 8);
    if (c == 0) { as2[n] = ps; ad2[n] = pd; }
}

// ---------------- K4: fused softmax + aggregation (layer 2) ----------------
// 16 lanes per dst node; 16 dst per 256-thread block.
__global__ __launch_bounds__(256) void k_agg2f(
    const int* __restrict__ row_ptr, const int* __restrict__ csr_src,
    const float* __restrict__ as2, const float* __restrict__ ad2,
    const float* __restrict__ h2, float* __restrict__ agg2)
{
    const int dst  = blockIdx.x * 16 + (threadIdx.x >> 4);
    const int lane = threadIdx.x & 15;
    const int start = row_ptr[dst], end = row_ptr[dst + 1];
    const float add = ad2[dst];

    // phase 1: online stats, one edge per lane, stride 16
    float m = -1e30f, den = 0.f;
    for (int i = start + lane; i < end; i += 16) {
        const float s = lrelu(as2[csr_src[i]] + add);
        const float M = fmaxf(m, s);
        den = den * __expf(m - M) + __expf(s - M);
        m = M;
    }
    #pragma unroll
    for (int mask = 1; mask < 16; mask <<= 1) {
        const float mo = __shfl_xor(m, mask);
        const float dn = __shfl_xor(den, mask);
        const float M  = fmaxf(m, mo);
        den = den * __expf(m - M) + dn * __expf(mo - M);
        m = M;
    }
    const float rden = 1.f / (den + 1e-16f);

    // phase 2: weighted gather (h2 is 6.4 MB -> L2-resident)
    float acc = 0.f;
    for (int i = start; i < end; ++i) {
        const int src = csr_src[i];
        const float s = lrelu(as2[src] + add);
        const float a = __expf(s - m) * rden;
        acc = fmaf(a, h2[(size_t)src * 16 + lane], acc);
    }
    agg2[(size_t)dst * 16 + lane] = acc;
}

// ---------------- K5: out = log_softmax(agg2 + b2) ----------------
__global__ __launch_bounds__(256) void k_out(
    const float* __restrict__ agg2, const float* __restrict__ b2,
    float* __restrict__ out)
{
    const int tid = threadIdx.x;
    const int n = blockIdx.x * 16 + (tid >> 4);
    const int c = tid & 15;
    const float v = agg2[(size_t)n * 16 + c] + b2[c];
    float m = v;
    m = fmaxf(m, __shfl_xor(m, 1)); m = fmaxf(m, __shfl_xor(m, 2));
    m = fmaxf(m, __shfl_xor(m, 4)); m = fmaxf(m, __shfl_xor(m, 8));
    float s = expf(v - m);
    s += __shfl_xor(s, 1); s += __shfl_xor(s, 2);
    s += __shfl_xor(s, 4); s += __shfl_xor(s, 8);
    out[(size_t)n * 16 + c] = v - m - logf(s);
}

extern "C" void kernel_launch(void* const* d_in, const int* in_sizes, int n_in,
                              void* d_out, int out_size, void* d_ws, size_t ws_size,
                              hipStream_t stream) {
    const float* x      = (const float*)d_in[0];
    const float* W1     = (const float*)d_in[1];
    const float* a_src1 = (const float*)d_in[2];
    const float* a_dst1 = (const float*)d_in[3];
    const float* b1     = (const float*)d_in[4];
    const float* W2     = (const float*)d_in[5];
    const float* a_src2 = (const float*)d_in[6];
    const float* a_dst2 = (const float*)d_in[7];
    const float* b2     = (const float*)d_in[8];
    const int*   ei     = (const int*)d_in[9];
    float* out = (float*)d_out;
    char* ws = (char*)d_ws;

    unsigned* h1b   = (unsigned*)(ws + 0);
    float* agg1     = (float*)(ws + 51200000);
    float* as1      = (float*)(ws + 102400000);
    float* ad1      = (float*)(ws + 104000000);
    int*   row_ptr  = (int*)(ws + 105600000);
    int*   cur      = (int*)(ws + 106000016);   // deg, then scatter cursor
    int*   partials = (int*)(ws + 106400016);
    int*   csr_src  = (int*)(ws + 106402064);
    unsigned short* W1T = (unsigned short*)(ws + 113202064);
    // layer-2 era (alias dead h1b region):
    float* h2   = (float*)(ws + 0);
    float* as2  = (float*)(ws + 6400000);
    float* ad2  = (float*)(ws + 6800000);
    float* agg2 = (float*)(ws + 7200000);

    const int EB = (EP + 255) / 256;

    // W1 transpose+cast, then dense transform via MFMA
    k_w1t<<<256, 128, 0, stream>>>(W1, W1T);
    k_gemm1m<<<1563, 256, 0, stream>>>(x, W1T, a_src1, a_dst1, h1b, as1, ad1);

    // CSR build
    hipMemsetAsync(cur, 0, 400000, stream);
    k_deg<<<EB, 256, 0, stream>>>(ei, cur);
    k_scan1<<<NBLK, 256, 0, stream>>>(cur, partials);
    k_scan2<<<1, 512, 0, stream>>>(partials);
    k_scan3<<<NBLK, 256, 0, stream>>>(partials, cur, row_ptr);
    k_scatter<<<EB, 256, 0, stream>>>(ei, cur, csr_src);

    // layer 1 attention + aggregation
    k_agg1f<<<25000, 256, 0, stream>>>(row_ptr, csr_src, as1, ad1, h1b, agg1);

    // layer 2
    k_gemm2<<<6250, 256, 0, stream>>>(agg1, b1, W2, a_src2, a_dst2, h2, as2, ad2);
    k_agg2f<<<6250, 256, 0, stream>>>(row_ptr, csr_src, as2, ad2, h2, agg2);
    k_out<<<6250, 256, 0, stream>>>(agg2, b2, out);
}

// Round 6
// 488.521 us; speedup vs baseline: 8.6088x; 1.3140x over previous
//
#include <hip/hip_runtime.h>
#include <hip/hip_bf16.h>
#include <math.h>

#define N_NODES 100000
#define N_EDGES 1600000
#define EP (N_EDGES + N_NODES)   // edges + self loops
#define F_IN 256
#define HIDDEN 32
#define HEADS 4
#define D1 (HEADS*HIDDEN)        // 128
#define NC 16
#define NEG_SLOPE 0.2f
#define NSTRIP 6250              // N_NODES / 16
#define NBUCK 391                // ceil(N_NODES/256) coarse buckets (dst>>8)
#define NCHUNKB 128              // chunk-blocks for bucket passes
#define CHUNK 13312              // 13*1024; 128*13312 >= EP

typedef __attribute__((ext_vector_type(8))) short bf16x8;
typedef __attribute__((ext_vector_type(4))) float f32x4;

// ---------------- workspace layout (bytes) ----------------
//   h1b     [N,64]  u32 @ 0           (25,600,000)  packed bf16 pairs
//   agg1    [N,128] f32 @ 51,200,000  (51,200,000)
//   as1     [N,4]   f32 @ 102,400,000 (1,600,000)
//   ad1     [N,4]   f32 @ 104,000,000 (1,600,000)
//   row_ptr [N+1]   i32 @ 105,600,000 (400,016)
//   histG   [391,128] u32 @ 106,000,016 (200,192)
//   csr_src [EP]    i32 @ 106,402,064 (6,800,000)
//   W1T     [128,256] bf16 @ 113,202,064 (65,536)
//   packed  [EP]    u32 @ 113,267,600 (6,800,000) -> ends 120,067,600
// layer-2 era (aliased into dead h1b region, written after k_agg1f):
//   h2 [N,16] @ 0   as2 [N] @ 6,400,000   ad2 [N] @ 6,800,000   agg2 [N,16] @ 7,200,000

__device__ __forceinline__ float lrelu(float x) { return x > 0.f ? x : NEG_SLOPE * x; }

// pack two f32 -> two bf16 (RNE) in one u32: lo in [15:0], hi in [31:16]
__device__ __forceinline__ unsigned bfpack(float lo, float hi) {
    unsigned a = __float_as_uint(lo), b = __float_as_uint(hi);
    a = (a + 0x7fffu + ((a >> 16) & 1u)) >> 16;
    b = (b + 0x7fffu + ((b >> 16) & 1u)) & 0xffff0000u;
    return a | b;
}
__device__ __forceinline__ unsigned short bf16r(float f) {
    unsigned a = __float_as_uint(f);
    return (unsigned short)((a + 0x7fffu + ((a >> 16) & 1u)) >> 16);
}
__device__ __forceinline__ float bflo(unsigned v) { return __uint_as_float(v << 16); }
__device__ __forceinline__ float bfhi(unsigned v) { return __uint_as_float(v & 0xffff0000u); }

// ---------------- CSR build: two-level counting sort ----------------
__global__ __launch_bounds__(256) void kA_hist(const int* __restrict__ ei,
                                               unsigned* __restrict__ histG) {
    __shared__ unsigned h[NBUCK];
    const int tid = threadIdx.x;
    for (int i = tid; i < NBUCK; i += 256) h[i] = 0;
    __syncthreads();
    const int base = blockIdx.x * CHUNK;
    const int lim = min(base + CHUNK, EP);
    for (int e = base + tid * 4; e + 3 < lim; e += 1024) {
        if (e < N_EDGES) {   // groups never straddle (N_EDGES % 4 == 0)
            const int4 d = *(const int4*)(ei + N_EDGES + e);
            atomicAdd(&h[d.x >> 8], 1u);
            atomicAdd(&h[d.y >> 8], 1u);
            atomicAdd(&h[d.z >> 8], 1u);
            atomicAdd(&h[d.w >> 8], 1u);
        } else {
            const int dst = e - N_EDGES;   // self loops: 4 consecutive dst
            atomicAdd(&h[dst >> 8], 1u);
            atomicAdd(&h[(dst + 1) >> 8], 1u);
            atomicAdd(&h[(dst + 2) >> 8], 1u);
            atomicAdd(&h[(dst + 3) >> 8], 1u);
        }
    }
    __syncthreads();
    for (int i = tid; i < NBUCK; i += 256) histG[i * NCHUNKB + blockIdx.x] = h[i];
}

__global__ __launch_bounds__(512) void kB_scan(unsigned* __restrict__ histG,
                                               int* __restrict__ row_ptr) {
    __shared__ unsigned sb[512];
    const int t = threadIdx.x;
    unsigned total = 0;
    if (t < NBUCK) {
        const uint4* p = (const uint4*)(histG + t * NCHUNKB);
        #pragma unroll
        for (int c = 0; c < NCHUNKB / 4; ++c) {
            const uint4 v = p[c];
            total += v.x + v.y + v.z + v.w;
        }
    }
    sb[t] = (t < NBUCK) ? total : 0;
    __syncthreads();
    for (int off = 1; off < 512; off <<= 1) {
        const unsigned u = (t >= off) ? sb[t - off] : 0;
        __syncthreads();
        sb[t] += u;
        __syncthreads();
    }
    if (t < NBUCK) {
        unsigned run = sb[t] - total;   // exclusive bucket base
        uint4* p = (uint4*)(histG + t * NCHUNKB);
        #pragma unroll
        for (int c = 0; c < NCHUNKB / 4; ++c) {
            uint4 v = p[c];
            uint4 o;
            o.x = run; run += v.x;
            o.y = run; run += v.y;
            o.z = run; run += v.z;
            o.w = run; run += v.w;
            p[c] = o;
        }
    }
    if (t == 0) row_ptr[N_NODES] = EP;
}

__global__ __launch_bounds__(256) void kC_bucket(const int* __restrict__ ei,
                                                 const unsigned* __restrict__ histG,
                                                 unsigned* __restrict__ packed) {
    __shared__ unsigned cur[NBUCK];
    const int tid = threadIdx.x;
    for (int i = tid; i < NBUCK; i += 256) cur[i] = histG[i * NCHUNKB + blockIdx.x];
    __syncthreads();
    const int base = blockIdx.x * CHUNK;
    const int lim = min(base + CHUNK, EP);
    for (int e = base + tid * 4; e + 3 < lim; e += 1024) {
        int4 s, d;
        if (e < N_EDGES) {
            s = *(const int4*)(ei + e);
            d = *(const int4*)(ei + N_EDGES + e);
        } else {
            s = make_int4(e - N_EDGES, e + 1 - N_EDGES, e + 2 - N_EDGES, e + 3 - N_EDGES);
            d = s;
        }
        unsigned p0 = atomicAdd(&cur[d.x >> 8], 1u);
        packed[p0] = ((unsigned)s.x << 8) | ((unsigned)d.x & 255u);
        unsigned p1 = atomicAdd(&cur[d.y >> 8], 1u);
        packed[p1] = ((unsigned)s.y << 8) | ((unsigned)d.y & 255u);
        unsigned p2 = atomicAdd(&cur[d.z >> 8], 1u);
        packed[p2] = ((unsigned)s.z << 8) | ((unsigned)d.z & 255u);
        unsigned p3 = atomicAdd(&cur[d.w >> 8], 1u);
        packed[p3] = ((unsigned)s.w << 8) | ((unsigned)d.w & 255u);
    }
}

__global__ __launch_bounds__(256) void kD_sort(const unsigned* __restrict__ histG,
                                               const unsigned* __restrict__ packed,
                                               int* __restrict__ row_ptr,
                                               int* __restrict__ csr_src) {
    __shared__ unsigned hist[256];
    __shared__ unsigned sb[256];
    __shared__ unsigned cur[256];
    const int b = blockIdx.x, tid = threadIdx.x;
    const unsigned start = histG[b * NCHUNKB];
    const unsigned end = (b + 1 < NBUCK) ? histG[(b + 1) * NCHUNKB] : (unsigned)EP;
    hist[tid] = 0;
    __syncthreads();
    for (unsigned i = start + tid; i < end; i += 256)
        atomicAdd(&hist[packed[i] & 255u], 1u);
    __syncthreads();
    const unsigned v = hist[tid];
    sb[tid] = v;
    __syncthreads();
    for (int off = 1; off < 256; off <<= 1) {
        const unsigned u = (tid >= off) ? sb[tid - off] : 0;
        __syncthreads();
        sb[tid] += u;
        __syncthreads();
    }
    const unsigned pos0 = start + sb[tid] - v;   // exclusive
    cur[tid] = pos0;
    const int node = b * 256 + tid;
    if (node < N_NODES) row_ptr[node] = (int)pos0;
    __syncthreads();
    for (unsigned i = start + tid; i < end; i += 256) {
        const unsigned pv = packed[i];
        const unsigned pos = atomicAdd(&cur[pv & 255u], 1u);
        csr_src[pos] = (int)(pv >> 8);
    }
}

// ---------------- W1 -> W1T bf16 [128][256] ----------------
__global__ __launch_bounds__(128) void k_w1t(const float* __restrict__ W1,
                                             unsigned short* __restrict__ W1T) {
    const int k = blockIdx.x;      // 0..255
    const int n = threadIdx.x;     // 0..127
    W1T[n * 256 + k] = bf16r(W1[k * 128 + n]);
}

// ---------------- K1: h1 = x @ W1 via MFMA bf16, fused as1/ad1 ----------------
__global__ __launch_bounds__(256) void k_gemm1m(
    const float* __restrict__ x, const unsigned short* __restrict__ W1T,
    const float* __restrict__ a_src1, const float* __restrict__ a_dst1,
    unsigned* __restrict__ h1b, float* __restrict__ as1, float* __restrict__ ad1)
{
    const int s = blockIdx.x * 4 + (threadIdx.x >> 6);
    if (s >= NSTRIP) return;
    const int lane = threadIdx.x & 63;
    const int q = lane & 15, g = lane >> 4;
    const int base = s * 16;
    const int row = base + q;
    const int kseg = g * 8;

    f32x4 acc[8];
    #pragma unroll
    for (int t = 0; t < 8; ++t) acc[t] = (f32x4){0.f, 0.f, 0.f, 0.f};

    #pragma unroll
    for (int kk = 0; kk < 8; ++kk) {
        const float4* xp = (const float4*)(x + (size_t)row * 256 + kk * 32 + kseg);
        const float4 xa = xp[0], xb = xp[1];
        union { unsigned u[4]; bf16x8 v; } A;
        A.u[0] = bfpack(xa.x, xa.y);
        A.u[1] = bfpack(xa.z, xa.w);
        A.u[2] = bfpack(xb.x, xb.y);
        A.u[3] = bfpack(xb.z, xb.w);
        #pragma unroll
        for (int t = 0; t < 8; ++t) {
            const bf16x8 B = *(const bf16x8*)(W1T + (size_t)(t * 16 + q) * 256 + kk * 32 + kseg);
            acc[t] = __builtin_amdgcn_mfma_f32_16x16x32_bf16(A.v, B, acc[t], 0, 0, 0);
        }
    }

    float ps[4][4], pd[4][4];
    #pragma unroll
    for (int h = 0; h < 4; ++h)
        #pragma unroll
        for (int r = 0; r < 4; ++r) { ps[h][r] = 0.f; pd[h][r] = 0.f; }
    #pragma unroll
    for (int t = 0; t < 8; ++t) {
        const int col = t * 16 + q;
        const float av = a_src1[col];
        const float dv = a_dst1[col];
        const int h = t >> 1;
        #pragma unroll
        for (int r = 0; r < 4; ++r) {
            ps[h][r] = fmaf(acc[t][r], av, ps[h][r]);
            pd[h][r] = fmaf(acc[t][r], dv, pd[h][r]);
        }
    }
    #pragma unroll
    for (int mask = 1; mask < 16; mask <<= 1) {
        #pragma unroll
        for (int h = 0; h < 4; ++h)
            #pragma unroll
            for (int r = 0; r < 4; ++r) {
                ps[h][r] += __shfl_xor(ps[h][r], mask);
                pd[h][r] += __shfl_xor(pd[h][r], mask);
            }
    }
    #pragma unroll
    for (int h = 0; h < 4; ++h)
        #pragma unroll
        for (int r = 0; r < 4; ++r)
            if (q == h * 4 + r) {
                const int n = base + g * 4 + r;
                as1[n * 4 + h] = ps[h][r];
                ad1[n * 4 + h] = pd[h][r];
            }

    #pragma unroll
    for (int t = 0; t < 8; ++t) {
        #pragma unroll
        for (int r = 0; r < 4; ++r) {
            const float other = __shfl_xor(acc[t][r], 1);
            if (!(q & 1)) {
                const int n = base + g * 4 + r;
                h1b[(size_t)n * 64 + t * 8 + (q >> 1)] = bfpack(acc[t][r], other);
            }
        }
    }
}

// ---------------- K2: fused softmax + aggregation (layer 1) ----------------
// One wave per dst node; phase 2 = half-wave per edge (2 edges in flight).
__global__ __launch_bounds__(256) void k_agg1f(
    const int* __restrict__ row_ptr, const int* __restrict__ csr_src,
    const float* __restrict__ as1, const float* __restrict__ ad1,
    const unsigned* __restrict__ h1b, float* __restrict__ agg1)
{
    const int dst  = blockIdx.x * 4 + (threadIdx.x >> 6);
    const int lane = threadIdx.x & 63;
    const int start = row_ptr[dst], end = row_ptr[dst + 1];

    // ---- phase 1: online softmax stats per head (16 edge slots x 4 heads) ----
    const int eh = lane >> 2;
    const int k  = lane & 3;
    const float adk = ad1[dst * 4 + k];
    float m = -1e30f, den = 0.f;
    for (int i = start + eh; i < end; i += 16) {
        const int src = csr_src[i];
        const float s = lrelu(as1[src * 4 + k] + adk);
        const float M = fmaxf(m, s);
        den = den * __expf(m - M) + __expf(s - M);
        m = M;
    }
    #pragma unroll
    for (int mask = 4; mask < 64; mask <<= 1) {
        const float mo = __shfl_xor(m, mask);
        const float dn = __shfl_xor(den, mask);
        const float M  = fmaxf(m, mo);
        den = den * __expf(m - M) + dn * __expf(mo - M);
        m = M;
    }

    // ---- phase 2: half-wave per edge; lane covers cols 4c..4c+3 ----
    const int hw = lane >> 5;          // edge parity
    const int c  = lane & 31;          // float4 col group
    const int oh = c >> 3;             // head of cols 4c..4c+3
    const float mh   = __shfl(m, oh);  // lane oh holds head oh stats
    const float rden = 1.f / (__shfl(den, oh) + 1e-16f);
    const float adh  = ad1[dst * 4 + oh];

    float4 acc = make_float4(0.f, 0.f, 0.f, 0.f);
    const uint2* h1v = (const uint2*)h1b;   // row stride = 32 uint2
    int i = start + hw;
    for (; i + 2 < end; i += 4) {
        const int s0 = csr_src[i], s1 = csr_src[i + 2];
        const float e0 = lrelu(as1[s0 * 4 + oh] + adh);
        const float e1 = lrelu(as1[s1 * 4 + oh] + adh);
        const uint2 v0 = h1v[(size_t)s0 * 32 + c];
        const uint2 v1 = h1v[(size_t)s1 * 32 + c];
        const float a0 = __expf(e0 - mh) * rden;
        const float a1 = __expf(e1 - mh) * rden;
        acc.x = fmaf(a0, bflo(v0.x), acc.x); acc.y = fmaf(a0, bfhi(v0.x), acc.y);
        acc.z = fmaf(a0, bflo(v0.y), acc.z); acc.w = fmaf(a0, bfhi(v0.y), acc.w);
        acc.x = fmaf(a1, bflo(v1.x), acc.x); acc.y = fmaf(a1, bfhi(v1.x), acc.y);
        acc.z = fmaf(a1, bflo(v1.y), acc.z); acc.w = fmaf(a1, bfhi(v1.y), acc.w);
    }
    if (i < end) {
        const int s0 = csr_src[i];
        const float e0 = lrelu(as1[s0 * 4 + oh] + adh);
        const uint2 v0 = h1v[(size_t)s0 * 32 + c];
        const float a0 = __expf(e0 - mh) * rden;
        acc.x = fmaf(a0, bflo(v0.x), acc.x); acc.y = fmaf(a0, bfhi(v0.x), acc.y);
        acc.z = fmaf(a0, bflo(v0.y), acc.z); acc.w = fmaf(a0, bfhi(v0.y), acc.w);
    }
    // combine the two half-wave partial sums
    acc.x += __shfl_xor(acc.x, 32);
    acc.y += __shfl_xor(acc.y, 32);
    acc.z += __shfl_xor(acc.z, 32);
    acc.w += __shfl_xor(acc.w, 32);
    if (hw == 0) ((float4*)agg1)[(size_t)dst * 32 + c] = acc;
}

// ---------------- K3: h2 = elu(agg1+b1) @ W2, fused as2/ad2 ----------------
__global__ __launch_bounds__(256) void k_gemm2(
    const float* __restrict__ agg1, const float* __restrict__ b1,
    const float* __restrict__ W2, const float* __restrict__ a_src2,
    const float* __restrict__ a_dst2,
    float* __restrict__ h2, float* __restrict__ as2, float* __restrict__ ad2)
{
    __shared__ float w2s[128 * 16];
    __shared__ float xs2[16 * 132];
    const int tid = threadIdx.x;
    const int base = blockIdx.x * 16;
    {
        const float4* wb = (const float4*)W2;
        float4* wd = (float4*)w2s;
        #pragma unroll
        for (int i = 0; i < 2; ++i) wd[tid + i * 256] = wb[tid + i * 256];
    }
    #pragma unroll
    for (int i = 0; i < 2; ++i) {
        const int idx = tid + i * 256;
        const int nl = idx >> 5;
        const int c4 = idx & 31;
        float4 v = ((const float4*)(agg1 + (size_t)(base + nl) * 128))[c4];
        const float4 b = ((const float4*)b1)[c4];
        v.x += b.x; v.y += b.y; v.z += b.z; v.w += b.w;
        v.x = v.x > 0.f ? v.x : expm1f(v.x);
        v.y = v.y > 0.f ? v.y : expm1f(v.y);
        v.z = v.z > 0.f ? v.z : expm1f(v.z);
        v.w = v.w > 0.f ? v.w : expm1f(v.w);
        *((float4*)(xs2 + nl * 132 + c4 * 4)) = v;
    }
    __syncthreads();
    const int nl = tid >> 4, c = tid & 15;
    float acc = 0.f;
    #pragma unroll
    for (int k = 0; k < 128; ++k)
        acc = fmaf(xs2[nl * 132 + k], w2s[k * 16 + c], acc);
    const int n = base + nl;
    h2[(size_t)n * 16 + c] = acc;
    float ps = acc * a_src2[c];
    float pd = acc * a_dst2[c];
    ps += __shfl_xor(ps, 1); ps += __shfl_xor(ps, 2); ps += __shfl_xor(ps, 4); ps += __shfl_xor(ps, 8);
    pd += __shfl_xor(pd, 1); pd += __shfl_xor(pd, 2); pd += __shfl_xor(pd, 4); pd += __shfl_xor(pd, 8);
    if (c == 0) { as2[n] = ps; ad2[n] = pd; }
}

// ---------------- K4: fused softmax + aggregation (layer 2) ----------------
__global__ __launch_bounds__(256) void k_agg2f(
    const int* __restrict__ row_ptr, const int* __restrict__ csr_src,
    const float* __restrict__ as2, const float* __restrict__ ad2,
    const float* __restrict__ h2, float* __restrict__ agg2)
{
    const int dst  = blockIdx.x * 16 + (threadIdx.x >> 4);
    const int lane = threadIdx.x & 15;
    const int start = row_ptr[dst], end = row_ptr[dst + 1];
    const float add = ad2[dst];

    float m = -1e30f, den = 0.f;
    for (int i = start + lane; i < end; i += 16) {
        const float s = lrelu(as2[csr_src[i]] + add);
        const float M = fmaxf(m, s);
        den = den * __expf(m - M) + __expf(s - M);
        m = M;
    }
    #pragma unroll
    for (int mask = 1; mask < 16; mask <<= 1) {
        const float mo = __shfl_xor(m, mask);
        const float dn = __shfl_xor(den, mask);
        const float M  = fmaxf(m, mo);
        den = den * __expf(m - M) + dn * __expf(mo - M);
        m = M;
    }
    const float rden = 1.f / (den + 1e-16f);

    float acc = 0.f;
    for (int i = start; i < end; ++i) {
        const int src = csr_src[i];
        const float s = lrelu(as2[src] + add);
        const float a = __expf(s - m) * rden;
        acc = fmaf(a, h2[(size_t)src * 16 + lane], acc);
    }
    agg2[(size_t)dst * 16 + lane] = acc;
}

// ---------------- K5: out = log_softmax(agg2 + b2) ----------------
__global__ __launch_bounds__(256) void k_out(
    const float* __restrict__ agg2, const float* __restrict__ b2,
    float* __restrict__ out)
{
    const int tid = threadIdx.x;
    const int n = blockIdx.x * 16 + (tid >> 4);
    const int c = tid & 15;
    const float v = agg2[(size_t)n * 16 + c] + b2[c];
    float m = v;
    m = fmaxf(m, __shfl_xor(m, 1)); m = fmaxf(m, __shfl_xor(m, 2));
    m = fmaxf(m, __shfl_xor(m, 4)); m = fmaxf(m, __shfl_xor(m, 8));
    float s = expf(v - m);
    s += __shfl_xor(s, 1); s += __shfl_xor(s, 2);
    s += __shfl_xor(s, 4); s += __shfl_xor(s, 8);
    out[(size_t)n * 16 + c] = v - m - logf(s);
}

extern "C" void kernel_launch(void* const* d_in, const int* in_sizes, int n_in,
                              void* d_out, int out_size, void* d_ws, size_t ws_size,
                              hipStream_t stream) {
    const float* x      = (const float*)d_in[0];
    const float* W1     = (const float*)d_in[1];
    const float* a_src1 = (const float*)d_in[2];
    const float* a_dst1 = (const float*)d_in[3];
    const float* b1     = (const float*)d_in[4];
    const float* W2     = (const float*)d_in[5];
    const float* a_src2 = (const float*)d_in[6];
    const float* a_dst2 = (const float*)d_in[7];
    const float* b2     = (const float*)d_in[8];
    const int*   ei     = (const int*)d_in[9];
    float* out = (float*)d_out;
    char* ws = (char*)d_ws;

    unsigned* h1b   = (unsigned*)(ws + 0);
    float* agg1     = (float*)(ws + 51200000);
    float* as1      = (float*)(ws + 102400000);
    float* ad1      = (float*)(ws + 104000000);
    int*   row_ptr  = (int*)(ws + 105600000);
    unsigned* histG = (unsigned*)(ws + 106000016);
    int*   csr_src  = (int*)(ws + 106402064);
    unsigned short* W1T = (unsigned short*)(ws + 113202064);
    unsigned* packed = (unsigned*)(ws + 113267600);
    // layer-2 era (alias dead h1b region):
    float* h2   = (float*)(ws + 0);
    float* as2  = (float*)(ws + 6400000);
    float* ad2  = (float*)(ws + 6800000);
    float* agg2 = (float*)(ws + 7200000);

    // dense transform via MFMA
    k_w1t<<<256, 128, 0, stream>>>(W1, W1T);
    k_gemm1m<<<1563, 256, 0, stream>>>(x, W1T, a_src1, a_dst1, h1b, as1, ad1);

    // CSR build: two-level counting sort (no global atomics, cache-local writes)
    kA_hist<<<NCHUNKB, 256, 0, stream>>>(ei, histG);
    kB_scan<<<1, 512, 0, stream>>>(histG, row_ptr);
    kC_bucket<<<NCHUNKB, 256, 0, stream>>>(ei, histG, packed);
    kD_sort<<<NBUCK, 256, 0, stream>>>(histG, packed, row_ptr, csr_src);

    // layer 1 attention + aggregation
    k_agg1f<<<25000, 256, 0, stream>>>(row_ptr, csr_src, as1, ad1, h1b, agg1);

    // layer 2
    k_gemm2<<<6250, 256, 0, stream>>>(agg1, b1, W2, a_src2, a_dst2, h2, as2, ad2);
    k_agg2f<<<6250, 256, 0, stream>>>(row_ptr, csr_src, as2, ad2, h2, agg2);
    k_out<<<6250, 256, 0, stream>>>(agg2, b2, out);
}

// Round 7
// 452.822 us; speedup vs baseline: 9.2875x; 1.0788x over previous
//
#include <hip/hip_runtime.h>
#include <hip/hip_bf16.h>
#include <math.h>

#define N_NODES 100000
#define N_EDGES 1600000
#define EP (N_EDGES + N_NODES)   // edges + self loops
#define F_IN 256
#define HIDDEN 32
#define HEADS 4
#define D1 (HEADS*HIDDEN)        // 128
#define NC 16
#define NEG_SLOPE 0.2f
#define NSTRIP 6250              // N_NODES / 16
#define NBUCK 391                // ceil(N_NODES/256) coarse buckets (dst>>8)
#define NCHUNKB 128              // chunk-blocks for bucket passes
#define CHUNK 13312              // 13*1024; 128*13312 >= EP

typedef __attribute__((ext_vector_type(8))) short bf16x8;
typedef __attribute__((ext_vector_type(4))) float f32x4;

// ---------------- workspace layout (bytes) ----------------
//   h1b     [N,64]  u32 @ 0           (25,600,000)  packed bf16 pairs
//   agg1b   [N,64]  u32 @ 51,200,000  (25,600,000)  packed bf16 pairs
//   as1     [N,4]   f32 @ 102,400,000 (1,600,000)
//   ad1     [N,4]   f32 @ 104,000,000 (1,600,000)
//   row_ptr [N+1]   i32 @ 105,600,000 (400,016)
//   histG   [391,128] u32 @ 106,000,016 (200,192)
//   csr_src [EP]    i32 @ 106,402,064 (6,800,000)
//   W1T     [128,256] bf16 @ 113,202,064 (65,536)
//   packed  [EP]    u32 @ 113,267,600 (6,800,000) -> ends 120,067,600
// layer-2 era (aliased into dead h1b region, written after k_agg1f):
//   h2b [N,8] u32 @ 0 (3,200,000)  as2 [N] @ 6,400,000  ad2 [N] @ 6,800,000
//   agg2 [N,16] f32 @ 7,200,000

__device__ __forceinline__ float lrelu(float x) { return x > 0.f ? x : NEG_SLOPE * x; }

// pack two f32 -> two bf16 (RNE) in one u32: lo in [15:0], hi in [31:16]
__device__ __forceinline__ unsigned bfpack(float lo, float hi) {
    unsigned a = __float_as_uint(lo), b = __float_as_uint(hi);
    a = (a + 0x7fffu + ((a >> 16) & 1u)) >> 16;
    b = (b + 0x7fffu + ((b >> 16) & 1u)) & 0xffff0000u;
    return a | b;
}
__device__ __forceinline__ unsigned short bf16r(float f) {
    unsigned a = __float_as_uint(f);
    return (unsigned short)((a + 0x7fffu + ((a >> 16) & 1u)) >> 16);
}
__device__ __forceinline__ float bflo(unsigned v) { return __uint_as_float(v << 16); }
__device__ __forceinline__ float bfhi(unsigned v) { return __uint_as_float(v & 0xffff0000u); }

// HBM -> LDS direct, 16 B per lane. LDS dest is wave-uniform base + lane*16;
// global src is per-lane (supports pre-swizzled source).
__device__ __forceinline__ void gload_lds16(const void* g, void* l) {
    __builtin_amdgcn_global_load_lds(
        (const __attribute__((address_space(1))) unsigned*)g,
        (__attribute__((address_space(3))) unsigned*)l,
        16, 0, 0);
}

// ---------------- CSR build: two-level counting sort ----------------
__global__ __launch_bounds__(256) void kA_hist(const int* __restrict__ ei,
                                               unsigned* __restrict__ histG) {
    __shared__ unsigned h[NBUCK];
    const int tid = threadIdx.x;
    for (int i = tid; i < NBUCK; i += 256) h[i] = 0;
    __syncthreads();
    const int base = blockIdx.x * CHUNK;
    const int lim = min(base + CHUNK, EP);
    for (int e = base + tid * 4; e + 3 < lim; e += 1024) {
        if (e < N_EDGES) {   // groups never straddle (N_EDGES % 4 == 0)
            const int4 d = *(const int4*)(ei + N_EDGES + e);
            atomicAdd(&h[d.x >> 8], 1u);
            atomicAdd(&h[d.y >> 8], 1u);
            atomicAdd(&h[d.z >> 8], 1u);
            atomicAdd(&h[d.w >> 8], 1u);
        } else {
            const int dst = e - N_EDGES;   // self loops: 4 consecutive dst
            atomicAdd(&h[dst >> 8], 1u);
            atomicAdd(&h[(dst + 1) >> 8], 1u);
            atomicAdd(&h[(dst + 2) >> 8], 1u);
            atomicAdd(&h[(dst + 3) >> 8], 1u);
        }
    }
    __syncthreads();
    for (int i = tid; i < NBUCK; i += 256) histG[i * NCHUNKB + blockIdx.x] = h[i];
}

__global__ __launch_bounds__(512) void kB_scan(unsigned* __restrict__ histG,
                                               int* __restrict__ row_ptr) {
    __shared__ unsigned sb[512];
    const int t = threadIdx.x;
    unsigned total = 0;
    if (t < NBUCK) {
        const uint4* p = (const uint4*)(histG + t * NCHUNKB);
        #pragma unroll
        for (int c = 0; c < NCHUNKB / 4; ++c) {
            const uint4 v = p[c];
            total += v.x + v.y + v.z + v.w;
        }
    }
    sb[t] = (t < NBUCK) ? total : 0;
    __syncthreads();
    for (int off = 1; off < 512; off <<= 1) {
        const unsigned u = (t >= off) ? sb[t - off] : 0;
        __syncthreads();
        sb[t] += u;
        __syncthreads();
    }
    if (t < NBUCK) {
        unsigned run = sb[t] - total;   // exclusive bucket base
        uint4* p = (uint4*)(histG + t * NCHUNKB);
        #pragma unroll
        for (int c = 0; c < NCHUNKB / 4; ++c) {
            uint4 v = p[c];
            uint4 o;
            o.x = run; run += v.x;
            o.y = run; run += v.y;
            o.z = run; run += v.z;
            o.w = run; run += v.w;
            p[c] = o;
        }
    }
    if (t == 0) row_ptr[N_NODES] = EP;
}

__global__ __launch_bounds__(256) void kC_bucket(const int* __restrict__ ei,
                                                 const unsigned* __restrict__ histG,
                                                 unsigned* __restrict__ packed) {
    __shared__ unsigned cur[NBUCK];
    const int tid = threadIdx.x;
    for (int i = tid; i < NBUCK; i += 256) cur[i] = histG[i * NCHUNKB + blockIdx.x];
    __syncthreads();
    const int base = blockIdx.x * CHUNK;
    const int lim = min(base + CHUNK, EP);
    for (int e = base + tid * 4; e + 3 < lim; e += 1024) {
        int4 s, d;
        if (e < N_EDGES) {
            s = *(const int4*)(ei + e);
            d = *(const int4*)(ei + N_EDGES + e);
        } else {
            s = make_int4(e - N_EDGES, e + 1 - N_EDGES, e + 2 - N_EDGES, e + 3 - N_EDGES);
            d = s;
        }
        unsigned p0 = atomicAdd(&cur[d.x >> 8], 1u);
        packed[p0] = ((unsigned)s.x << 8) | ((unsigned)d.x & 255u);
        unsigned p1 = atomicAdd(&cur[d.y >> 8], 1u);
        packed[p1] = ((unsigned)s.y << 8) | ((unsigned)d.y & 255u);
        unsigned p2 = atomicAdd(&cur[d.z >> 8], 1u);
        packed[p2] = ((unsigned)s.z << 8) | ((unsigned)d.z & 255u);
        unsigned p3 = atomicAdd(&cur[d.w >> 8], 1u);
        packed[p3] = ((unsigned)s.w << 8) | ((unsigned)d.w & 255u);
    }
}

__global__ __launch_bounds__(256) void kD_sort(const unsigned* __restrict__ histG,
                                               const unsigned* __restrict__ packed,
                                               int* __restrict__ row_ptr,
                                               int* __restrict__ csr_src) {
    __shared__ unsigned hist[256];
    __shared__ unsigned sb[256];
    __shared__ unsigned cur[256];
    const int b = blockIdx.x, tid = threadIdx.x;
    const unsigned start = histG[b * NCHUNKB];
    const unsigned end = (b + 1 < NBUCK) ? histG[(b + 1) * NCHUNKB] : (unsigned)EP;
    hist[tid] = 0;
    __syncthreads();
    for (unsigned i = start + tid; i < end; i += 256)
        atomicAdd(&hist[packed[i] & 255u], 1u);
    __syncthreads();
    const unsigned v = hist[tid];
    sb[tid] = v;
    __syncthreads();
    for (int off = 1; off < 256; off <<= 1) {
        const unsigned u = (tid >= off) ? sb[tid - off] : 0;
        __syncthreads();
        sb[tid] += u;
        __syncthreads();
    }
    const unsigned pos0 = start + sb[tid] - v;   // exclusive
    cur[tid] = pos0;
    const int node = b * 256 + tid;
    if (node < N_NODES) row_ptr[node] = (int)pos0;
    __syncthreads();
    for (unsigned i = start + tid; i < end; i += 256) {
        const unsigned pv = packed[i];
        const unsigned pos = atomicAdd(&cur[pv & 255u], 1u);
        csr_src[pos] = (int)(pv >> 8);
    }
}

// ---------------- W1 -> W1T bf16 [128][256] ----------------
__global__ __launch_bounds__(128) void k_w1t(const float* __restrict__ W1,
                                             unsigned short* __restrict__ W1T) {
    const int k = blockIdx.x;      // 0..255
    const int n = threadIdx.x;     // 0..127
    W1T[n * 256 + k] = bf16r(W1[k * 128 + n]);
}

// ---------------- K1: h1 = x @ W1 via MFMA bf16, fused as1/ad1 ----------------
// 64 rows/block staged HBM->LDS via global_load_lds (swizzled source);
// 4 waves, one 16-row strip each.
__global__ __launch_bounds__(256) void k_gemm1m(
    const float* __restrict__ x, const unsigned short* __restrict__ W1T,
    const float* __restrict__ a_src1, const float* __restrict__ a_dst1,
    unsigned* __restrict__ h1b, float* __restrict__ as1, float* __restrict__ ad1)
{
    __shared__ float xs[64 * 256];   // 64 KB, granule-swizzled rows
    const int wv = threadIdx.x >> 6;
    const int lane = threadIdx.x & 63;
    const int s = blockIdx.x * 4 + wv;
    const int base = s * 16;

    // ---- stage: wave wv stages its own 16 rows; source granule XOR (row&7)
    #pragma unroll
    for (int i = 0; i < 16; ++i) {
        const int r = wv * 16 + i;                  // local row 0..63
        int grow = blockIdx.x * 64 + r;
        if (grow >= N_NODES) grow = N_NODES - 1;    // clamp (dup harmless)
        const unsigned gr = (unsigned)lane ^ (unsigned)(r & 7);   // 16B granule
        const char* gsrc = (const char*)(x + (size_t)grow * 256) + gr * 16;
        gload_lds16(gsrc, (char*)xs + r * 1024);
    }
    __syncthreads();

    if (s < NSTRIP) {
        const int q = lane & 15, g = lane >> 4;
        const int kseg = g * 8;
        const int rowb = (wv * 16 + q) * 1024;      // this lane's LDS row base
        const int sw = q & 7;

        f32x4 acc[8];
        #pragma unroll
        for (int t = 0; t < 8; ++t) acc[t] = (f32x4){0.f, 0.f, 0.f, 0.f};

        #pragma unroll
        for (int kk = 0; kk < 8; ++kk) {
            const int u = kk * 8 + g * 2;           // 16B granule (4 f32)
            const int ua = (u ^ sw) * 16;
            const float4 f0 = *(const float4*)((const char*)xs + rowb + ua);         // cols 4u..4u+3
            const float4 f1 = *(const float4*)((const char*)xs + rowb + (ua ^ 16));  // cols 4u+4..
            union { unsigned u4[4]; bf16x8 v; } A;
            A.u4[0] = bfpack(f0.x, f0.y);
            A.u4[1] = bfpack(f0.z, f0.w);
            A.u4[2] = bfpack(f1.x, f1.y);
            A.u4[3] = bfpack(f1.z, f1.w);
            #pragma unroll
            for (int t = 0; t < 8; ++t) {
                const bf16x8 B = *(const bf16x8*)(W1T + (size_t)(t * 16 + q) * 256 + kk * 32 + kseg);
                acc[t] = __builtin_amdgcn_mfma_f32_16x16x32_bf16(A.v, B, acc[t], 0, 0, 0);
            }
        }

        // ---- epilogue: as1/ad1 per-head dots ----
        float ps[4][4], pd[4][4];
        #pragma unroll
        for (int h = 0; h < 4; ++h)
            #pragma unroll
            for (int r = 0; r < 4; ++r) { ps[h][r] = 0.f; pd[h][r] = 0.f; }
        #pragma unroll
        for (int t = 0; t < 8; ++t) {
            const int col = t * 16 + q;
            const float av = a_src1[col];
            const float dv = a_dst1[col];
            const int h = t >> 1;
            #pragma unroll
            for (int r = 0; r < 4; ++r) {
                ps[h][r] = fmaf(acc[t][r], av, ps[h][r]);
                pd[h][r] = fmaf(acc[t][r], dv, pd[h][r]);
            }
        }
        #pragma unroll
        for (int mask = 1; mask < 16; mask <<= 1) {
            #pragma unroll
            for (int h = 0; h < 4; ++h)
                #pragma unroll
                for (int r = 0; r < 4; ++r) {
                    ps[h][r] += __shfl_xor(ps[h][r], mask);
                    pd[h][r] += __shfl_xor(pd[h][r], mask);
                }
        }
        #pragma unroll
        for (int h = 0; h < 4; ++h)
            #pragma unroll
            for (int r = 0; r < 4; ++r)
                if (q == h * 4 + r) {
                    const int n = base + g * 4 + r;
                    as1[n * 4 + h] = ps[h][r];
                    ad1[n * 4 + h] = pd[h][r];
                }

        #pragma unroll
        for (int t = 0; t < 8; ++t) {
            #pragma unroll
            for (int r = 0; r < 4; ++r) {
                const float other = __shfl_xor(acc[t][r], 1);
                if (!(q & 1)) {
                    const int n = base + g * 4 + r;
                    h1b[(size_t)n * 64 + t * 8 + (q >> 1)] = bfpack(acc[t][r], other);
                }
            }
        }
    }
}

// ---------------- K2: fused softmax + aggregation (layer 1) ----------------
// One wave per dst; phase 2 = quarter-wave per edge (uint4/lane, 8 rows in flight).
__global__ __launch_bounds__(256) void k_agg1f(
    const int* __restrict__ row_ptr, const int* __restrict__ csr_src,
    const float* __restrict__ as1, const float* __restrict__ ad1,
    const unsigned* __restrict__ h1b, unsigned* __restrict__ agg1b)
{
    const int dst  = blockIdx.x * 4 + (threadIdx.x >> 6);
    const int lane = threadIdx.x & 63;
    const int start = row_ptr[dst], end = row_ptr[dst + 1];

    // ---- phase 1: online softmax stats per head (16 edge slots x 4 heads) ----
    const int eh = lane >> 2;
    const int k  = lane & 3;
    const float adk = ad1[dst * 4 + k];
    float m = -1e30f, den = 0.f;
    for (int i = start + eh; i < end; i += 16) {
        const int src = csr_src[i];
        const float sv = lrelu(as1[src * 4 + k] + adk);
        const float M = fmaxf(m, sv);
        den = den * __expf(m - M) + __expf(sv - M);
        m = M;
    }
    #pragma unroll
    for (int mask = 4; mask < 64; mask <<= 1) {
        const float mo = __shfl_xor(m, mask);
        const float dn = __shfl_xor(den, mask);
        const float M  = fmaxf(m, mo);
        den = den * __expf(m - M) + dn * __expf(mo - M);
        m = M;
    }

    // ---- phase 2: quarter-wave per edge; lane covers cols 8c..8c+7 ----
    const int ql = lane >> 4;          // edge slot 0..3
    const int c  = lane & 15;          // uint4 col group
    const int oh = c >> 2;             // head of cols 8c..
    const float mh   = __shfl(m, oh);  // lane oh holds head oh stats
    const float rden = 1.f / (__shfl(den, oh) + 1e-16f);
    const float adh  = ad1[dst * 4 + oh];

    float acc[8];
    #pragma unroll
    for (int j = 0; j < 8; ++j) acc[j] = 0.f;
    const uint4* h1v = (const uint4*)h1b;   // row = 16 uint4
    int i = start + ql;
    for (; i + 4 < end; i += 8) {
        const int s0 = csr_src[i], s1 = csr_src[i + 4];
        const float e0 = lrelu(as1[s0 * 4 + oh] + adh);
        const float e1 = lrelu(as1[s1 * 4 + oh] + adh);
        const uint4 v0 = h1v[(size_t)s0 * 16 + c];
        const uint4 v1 = h1v[(size_t)s1 * 16 + c];
        const float w0 = __expf(e0 - mh) * rden;
        const float w1 = __expf(e1 - mh) * rden;
        acc[0] = fmaf(w0, bflo(v0.x), acc[0]); acc[1] = fmaf(w0, bfhi(v0.x), acc[1]);
        acc[2] = fmaf(w0, bflo(v0.y), acc[2]); acc[3] = fmaf(w0, bfhi(v0.y), acc[3]);
        acc[4] = fmaf(w0, bflo(v0.z), acc[4]); acc[5] = fmaf(w0, bfhi(v0.z), acc[5]);
        acc[6] = fmaf(w0, bflo(v0.w), acc[6]); acc[7] = fmaf(w0, bfhi(v0.w), acc[7]);
        acc[0] = fmaf(w1, bflo(v1.x), acc[0]); acc[1] = fmaf(w1, bfhi(v1.x), acc[1]);
        acc[2] = fmaf(w1, bflo(v1.y), acc[2]); acc[3] = fmaf(w1, bfhi(v1.y), acc[3]);
        acc[4] = fmaf(w1, bflo(v1.z), acc[4]); acc[5] = fmaf(w1, bfhi(v1.z), acc[5]);
        acc[6] = fmaf(w1, bflo(v1.w), acc[6]); acc[7] = fmaf(w1, bfhi(v1.w), acc[7]);
    }
    if (i < end) {
        const int s0 = csr_src[i];
        const float e0 = lrelu(as1[s0 * 4 + oh] + adh);
        const uint4 v0 = h1v[(size_t)s0 * 16 + c];
        const float w0 = __expf(e0 - mh) * rden;
        acc[0] = fmaf(w0, bflo(v0.x), acc[0]); acc[1] = fmaf(w0, bfhi(v0.x), acc[1]);
        acc[2] = fmaf(w0, bflo(v0.y), acc[2]); acc[3] = fmaf(w0, bfhi(v0.y), acc[3]);
        acc[4] = fmaf(w0, bflo(v0.z), acc[4]); acc[5] = fmaf(w0, bfhi(v0.z), acc[5]);
        acc[6] = fmaf(w0, bflo(v0.w), acc[6]); acc[7] = fmaf(w0, bfhi(v0.w), acc[7]);
    }
    #pragma unroll
    for (int j = 0; j < 8; ++j) {
        acc[j] += __shfl_xor(acc[j], 16);
        acc[j] += __shfl_xor(acc[j], 32);
    }
    if (ql == 0) {
        uint4 o;
        o.x = bfpack(acc[0], acc[1]);
        o.y = bfpack(acc[2], acc[3]);
        o.z = bfpack(acc[4], acc[5]);
        o.w = bfpack(acc[6], acc[7]);
        ((uint4*)agg1b)[(size_t)dst * 16 + c] = o;
    }
}

// ---------------- K3: h2 = elu(agg1+b1) @ W2, fused as2/ad2 ----------------
__global__ __launch_bounds__(256) void k_gemm2(
    const unsigned* __restrict__ agg1b, const float* __restrict__ b1,
    const float* __restrict__ W2, const float* __restrict__ a_src2,
    const float* __restrict__ a_dst2,
    unsigned* __restrict__ h2b, float* __restrict__ as2, float* __restrict__ ad2)
{
    __shared__ float w2s[128 * 16];
    __shared__ float xs2[16 * 132];
    const int tid = threadIdx.x;
    const int base = blockIdx.x * 16;
    {
        const float4* wb = (const float4*)W2;
        float4* wd = (float4*)w2s;
        #pragma unroll
        for (int i = 0; i < 2; ++i) wd[tid + i * 256] = wb[tid + i * 256];
    }
    {   // stage elu(agg1+b1): 16 rows x 16 uint4, one per thread
        const int row = tid >> 4;
        const int u = tid & 15;
        const uint4 v = ((const uint4*)agg1b)[(size_t)(base + row) * 16 + u];
        const float4 bb0 = ((const float4*)b1)[u * 2];
        const float4 bb1 = ((const float4*)b1)[u * 2 + 1];
        float e[8] = { bflo(v.x) + bb0.x, bfhi(v.x) + bb0.y,
                       bflo(v.y) + bb0.z, bfhi(v.y) + bb0.w,
                       bflo(v.z) + bb1.x, bfhi(v.z) + bb1.y,
                       bflo(v.w) + bb1.z, bfhi(v.w) + bb1.w };
        #pragma unroll
        for (int j = 0; j < 8; ++j) e[j] = e[j] > 0.f ? e[j] : expm1f(e[j]);
        #pragma unroll
        for (int j = 0; j < 8; ++j) xs2[row * 132 + u * 8 + j] = e[j];
    }
    __syncthreads();
    const int nl = tid >> 4, c = tid & 15;
    float acc = 0.f;
    #pragma unroll
    for (int k = 0; k < 128; ++k)
        acc = fmaf(xs2[nl * 132 + k], w2s[k * 16 + c], acc);
    const int n = base + nl;
    const float other = __shfl_xor(acc, 1);
    if (!(c & 1)) h2b[(size_t)n * 8 + (c >> 1)] = bfpack(acc, other);
    float ps = acc * a_src2[c];
    float pd = acc * a_dst2[c];
    ps += __shfl_xor(ps, 1); ps += __shfl_xor(ps, 2); ps += __shfl_xor(ps, 4); ps += __shfl_xor(ps, 8);
    pd += __shfl_xor(pd, 1); pd += __shfl_xor(pd, 2); pd += __shfl_xor(pd, 4); pd += __shfl_xor(pd, 8);
    if (c == 0) { as2[n] = ps; ad2[n] = pd; }
}

// ---------------- K4: fused softmax + aggregation (layer 2) ----------------
__global__ __launch_bounds__(256) void k_agg2f(
    const int* __restrict__ row_ptr, const int* __restrict__ csr_src,
    const float* __restrict__ as2, const float* __restrict__ ad2,
    const unsigned* __restrict__ h2b, float* __restrict__ agg2)
{
    const int dst  = blockIdx.x * 16 + (threadIdx.x >> 4);
    const int lane = threadIdx.x & 15;
    const int start = row_ptr[dst], end = row_ptr[dst + 1];
    const float add = ad2[dst];

    float m = -1e30f, den = 0.f;
    for (int i = start + lane; i < end; i += 16) {
        const float sv = lrelu(as2[csr_src[i]] + add);
        const float M = fmaxf(m, sv);
        den = den * __expf(m - M) + __expf(sv - M);
        m = M;
    }
    #pragma unroll
    for (int mask = 1; mask < 16; mask <<= 1) {
        const float mo = __shfl_xor(m, mask);
        const float dn = __shfl_xor(den, mask);
        const float M  = fmaxf(m, mo);
        den = den * __expf(m - M) + dn * __expf(mo - M);
        m = M;
    }
    const float rden = 1.f / (den + 1e-16f);

    float acc = 0.f;
    const unsigned hsel = lane >> 1;
    int i = start;
    for (; i + 1 < end; i += 2) {
        const int s0 = csr_src[i], s1 = csr_src[i + 1];
        const float e0 = lrelu(as2[s0] + add);
        const float e1 = lrelu(as2[s1] + add);
        const unsigned hv0 = h2b[(size_t)s0 * 8 + hsel];
        const unsigned hv1 = h2b[(size_t)s1 * 8 + hsel];
        const float w0 = __expf(e0 - m) * rden;
        const float w1 = __expf(e1 - m) * rden;
        acc = fmaf(w0, (lane & 1) ? bfhi(hv0) : bflo(hv0), acc);
        acc = fmaf(w1, (lane & 1) ? bfhi(hv1) : bflo(hv1), acc);
    }
    if (i < end) {
        const int s0 = csr_src[i];
        const float e0 = lrelu(as2[s0] + add);
        const unsigned hv0 = h2b[(size_t)s0 * 8 + hsel];
        const float w0 = __expf(e0 - m) * rden;
        acc = fmaf(w0, (lane & 1) ? bfhi(hv0) : bflo(hv0), acc);
    }
    agg2[(size_t)dst * 16 + lane] = acc;
}

// ---------------- K5: out = log_softmax(agg2 + b2) ----------------
__global__ __launch_bounds__(256) void k_out(
    const float* __restrict__ agg2, const float* __restrict__ b2,
    float* __restrict__ out)
{
    const int tid = threadIdx.x;
    const int n = blockIdx.x * 16 + (tid >> 4);
    const int c = tid & 15;
    const float v = agg2[(size_t)n * 16 + c] + b2[c];
    float m = v;
    m = fmaxf(m, __shfl_xor(m, 1)); m = fmaxf(m, __shfl_xor(m, 2));
    m = fmaxf(m, __shfl_xor(m, 4)); m = fmaxf(m, __shfl_xor(m, 8));
    float s = expf(v - m);
    s += __shfl_xor(s, 1); s += __shfl_xor(s, 2);
    s += __shfl_xor(s, 4); s += __shfl_xor(s, 8);
    out[(size_t)n * 16 + c] = v - m - logf(s);
}

extern "C" void kernel_launch(void* const* d_in, const int* in_sizes, int n_in,
                              void* d_out, int out_size, void* d_ws, size_t ws_size,
                              hipStream_t stream) {
    const float* x      = (const float*)d_in[0];
    const float* W1     = (const float*)d_in[1];
    const float* a_src1 = (const float*)d_in[2];
    const float* a_dst1 = (const float*)d_in[3];
    const float* b1     = (const float*)d_in[4];
    const float* W2     = (const float*)d_in[5];
    const float* a_src2 = (const float*)d_in[6];
    const float* a_dst2 = (const float*)d_in[7];
    const float* b2     = (const float*)d_in[8];
    const int*   ei     = (const int*)d_in[9];
    float* out = (float*)d_out;
    char* ws = (char*)d_ws;

    unsigned* h1b   = (unsigned*)(ws + 0);
    unsigned* agg1b = (unsigned*)(ws + 51200000);
    float* as1      = (float*)(ws + 102400000);
    float* ad1      = (float*)(ws + 104000000);
    int*   row_ptr  = (int*)(ws + 105600000);
    unsigned* histG = (unsigned*)(ws + 106000016);
    int*   csr_src  = (int*)(ws + 106402064);
    unsigned short* W1T = (unsigned short*)(ws + 113202064);
    unsigned* packed = (unsigned*)(ws + 113267600);
    // layer-2 era (alias dead h1b region):
    unsigned* h2b  = (unsigned*)(ws + 0);
    float* as2  = (float*)(ws + 6400000);
    float* ad2  = (float*)(ws + 6800000);
    float* agg2 = (float*)(ws + 7200000);

    // dense transform via MFMA
    k_w1t<<<256, 128, 0, stream>>>(W1, W1T);
    k_gemm1m<<<1563, 256, 0, stream>>>(x, W1T, a_src1, a_dst1, h1b, as1, ad1);

    // CSR build: two-level counting sort (no global atomics, cache-local writes)
    kA_hist<<<NCHUNKB, 256, 0, stream>>>(ei, histG);
    kB_scan<<<1, 512, 0, stream>>>(histG, row_ptr);
    kC_bucket<<<NCHUNKB, 256, 0, stream>>>(ei, histG, packed);
    kD_sort<<<NBUCK, 256, 0, stream>>>(histG, packed, row_ptr, csr_src);

    // layer 1 attention + aggregation
    k_agg1f<<<25000, 256, 0, stream>>>(row_ptr, csr_src, as1, ad1, h1b, agg1b);

    // layer 2
    k_gemm2<<<6250, 256, 0, stream>>>(agg1b, b1, W2, a_src2, a_dst2, h2b, as2, ad2);
    k_agg2f<<<6250, 256, 0, stream>>>(row_ptr, csr_src, as2, ad2, h2b, agg2);
    k_out<<<6250, 256, 0, stream>>>(agg2, b2, out);
}